// Round 5
// baseline (828.194 us; speedup 1.0000x reference)
//
#include <hip/hip_runtime.h>
#include <stdint.h>

#define BB 16
#define CC 512
#define NN 4096
#define KC 64

typedef unsigned short ushort_t;
typedef __attribute__((ext_vector_type(8))) __bf16 bf16x8;
typedef __attribute__((ext_vector_type(4))) float f32x4;

static __device__ __forceinline__ float bu2f(ushort_t u){
  union{unsigned int i; float f;} v; v.i = ((unsigned int)u)<<16; return v.f;
}
static __device__ __forceinline__ ushort_t f2bu(float f){
  unsigned int x = __float_as_uint(f);
  return (ushort_t)((x + 0x7FFFu + ((x>>16)&1u)) >> 16);
}
static __device__ __forceinline__ ushort_t lo_part(float v, ushort_t hi){
  return f2bu(v - bu2f(hi));
}

#define MFMA16(a,b,c) __builtin_amdgcn_mfma_f32_16x16x32_bf16(a,b,c,0,0,0)

// ---- staging: ROWS x 64 bf16 tile, global (row-major, ld elems) -> LDS ----
// LDS layout: linear 128B rows (pitch 64 elems), 16B segments XOR-swizzled:
//   LDS[row][s] holds global[row][s ^ (row&7)]  (s = 16B segment index 0..7)
// Loaded via global_load_lds(16B): dest is wave-uniform base + lane*16B, so
// the swizzle is applied on the per-lane GLOBAL source address (m173/m201).
template<int ROWS>
static __device__ __forceinline__ void stage_lds(const ushort_t* __restrict__ g, int ld,
                                                 ushort_t* l, int tid){
  int wid = tid >> 6, lane = tid & 63;
  #pragma unroll
  for (int it = 0; it < ROWS/32; ++it){
    int chunk = it*4 + wid;              // 1024B (8 rows) per wave-instruction
    int row = chunk*8 + (lane >> 3);
    int seg = (lane & 7) ^ (row & 7);    // pre-swizzled source segment
    const ushort_t* gp = g + (size_t)row*ld + seg*8;
    ushort_t* lp = l + chunk*512;        // wave-uniform; HW adds lane*16B
    __builtin_amdgcn_global_load_lds(
        (const __attribute__((address_space(1))) void*)gp,
        (__attribute__((address_space(3))) void*)lp, 16, 0, 0);
  }
}
// fragment read applies the same XOR involution (ko is a multiple of 8)
static __device__ __forceinline__ bf16x8 frag_ld(const ushort_t* l, int row, int ko){
  return *(const bf16x8*)(l + row*64 + (ko ^ ((row & 7) << 3)));
}

// ---------------- transpose x[b][c][n] (f32) -> xT planes [b][n][c] (bf16 hi/lo) ----------------
__global__ __launch_bounds__(256) void k_transpose(const float* __restrict__ x,
    ushort_t* __restrict__ xTh, ushort_t* __restrict__ xTl, int hasLo){
  __shared__ ushort_t th[64][68];
  __shared__ ushort_t tl[64][68];
  int b = blockIdx.z, c0 = blockIdx.y*64, n0 = blockIdx.x*64;
  int r16 = threadIdx.x >> 4;
  int q4  = (threadIdx.x & 15) * 4;
  #pragma unroll
  for (int p = 0; p < 4; ++p){
    int row = r16 + p*16;   // c index within tile
    size_t off = ((size_t)b*CC + c0 + row)*NN + n0 + q4;
    float4 v = *(const float4*)(x + off);
    ushort_t h0=f2bu(v.x), h1=f2bu(v.y), h2=f2bu(v.z), h3=f2bu(v.w);
    th[q4+0][row]=h0; th[q4+1][row]=h1; th[q4+2][row]=h2; th[q4+3][row]=h3;
    if (hasLo){
      tl[q4+0][row]=lo_part(v.x,h0); tl[q4+1][row]=lo_part(v.y,h1);
      tl[q4+2][row]=lo_part(v.z,h2); tl[q4+3][row]=lo_part(v.w,h3);
    }
  }
  __syncthreads();
  #pragma unroll
  for (int p = 0; p < 4; ++p){
    int nrow = r16 + p*16;
    size_t off = ((size_t)b*NN + n0 + nrow)*CC + c0 + q4;
    ushort4 v;
    v.x = th[nrow][q4+0]; v.y = th[nrow][q4+1]; v.z = th[nrow][q4+2]; v.w = th[nrow][q4+3];
    *(ushort4*)(xTh + off) = v;
    if (hasLo){
      ushort4 u;
      u.x = tl[nrow][q4+0]; u.y = tl[nrow][q4+1]; u.z = tl[nrow][q4+2]; u.w = tl[nrow][q4+3];
      *(ushort4*)(xTl + off) = u;
    }
  }
}

// ---------------- prep: W1/W1T/W2 hi-lo, mu->mT hi-lo, BN affine, bias ----------------
__global__ __launch_bounds__(256) void k_prep(const float* __restrict__ gamma,
    const float* __restrict__ beta, const float* __restrict__ mean,
    const float* __restrict__ var, const float* __restrict__ b1,
    const float* __restrict__ W1, const float* __restrict__ W2,
    const float* __restrict__ mu,
    float* __restrict__ bnscale, float* __restrict__ bnshift,
    float* __restrict__ b1f,
    ushort_t* __restrict__ W1Th, ushort_t* __restrict__ W1Tl,
    ushort_t* __restrict__ W2h, ushort_t* __restrict__ W2l,
    ushort_t* __restrict__ mTh, ushort_t* __restrict__ mTl){
  int t = blockIdx.x*256 + threadIdx.x;
  if (t < CC){
    float inv = gamma[t] * rsqrtf(var[t] + 1e-5f);
    bnscale[t] = inv;
    bnshift[t] = beta[t] - mean[t]*inv;
    b1f[t] = b1[t];
  }
  if (t < CC*CC){
    int o = t >> 9, c = t & (CC-1);
    float w1 = W1[t], w2 = W2[t];
    ushort_t h1 = f2bu(w1), h2 = f2bu(w2);
    // W1 transposed planes [c][o] for the P = W1^T m GEMM
    W1Th[(size_t)c*CC + o] = h1; W1Tl[(size_t)c*CC + o] = lo_part(w1,h1);
    W2h[t] = h2; W2l[t] = lo_part(w2,h2);
  }
  if (t < BB*KC*CC){
    int c = t & (CC-1);
    int k = (t >> 9) & (KC-1);
    float v = mu[(size_t)c*KC + k];
    ushort_t h = f2bu(v);
    mTh[t] = h; mTl[t] = lo_part(v,h);
  }
}

// ---------------- conv1: x1 = W1 @ x + b -> xf[c][n] only (hi/lo planes) ----------------
// NOTE: xt1 ([n][c] copy) eliminated — logits now computed from xT and P=W1^T m.
__global__ __launch_bounds__(256) void k_conv1(const ushort_t* __restrict__ W1Th,
    const ushort_t* __restrict__ W1Tl, const float* __restrict__ bias,
    const ushort_t* __restrict__ xTh, const ushort_t* __restrict__ xTl, int hasBl,
    ushort_t* __restrict__ xfh, ushort_t* __restrict__ xfl, int hasxfl){
  __shared__ __align__(16) ushort_t sm[4*128*64];
  ushort_t* lAh = sm;
  ushort_t* lAl = sm + 128*64;
  ushort_t* lBh = sm + 2*128*64;
  ushort_t* lBl = sm + 3*128*64;
  int b = blockIdx.z, m0 = blockIdx.y*128, n0 = blockIdx.x*128;
  int tid = threadIdx.x, wid = tid>>6, lane = tid&63, quad = lane>>4, l16 = lane&15;
  int wm = wid>>1, wn = wid&1;
  f32x4 zero4 = {0.f,0.f,0.f,0.f};
  f32x4 acc[4][4];
  #pragma unroll
  for (int i=0;i<4;++i){
    #pragma unroll
    for (int j=0;j<4;++j) acc[i][j] = zero4;
  }
  // A = W1 rows m (o-dim), K = c: W1[m][c] = W1Th transposed back... we need
  // W1 row-major [o][c]; W1Th is [c][o]. Use W1Th with roles swapped:
  // acc[m][n]: A rows = o (output channel). W1 row o, k-chunk c -> read from
  // W1Th[c][o] would be strided. Instead stage A from W1Th as B-side? Simpler:
  // A tile rows o need W1[o][c]; reconstruct via W1Th with ld trick is wrong.
  // So stage A from the original-orientation view: W1Th[(c)*CC + o] means
  // W1[o][c] = W1Th[c*CC + o] -> rows of o are strided. To keep coalesced
  // staging we instead compute acc as D[c-rows?]. Simplest correct option:
  // swap operands: D[n][m]? Keep original W1 planes too? -> We keep using
  // W1Th as the [c][o] matrix and compute conv1 output transposed per-tile:
  // D[o][n] with A rows o requires W1[o][c]. We therefore ALSO pass bias and
  // use the mathematically identical form: stage A from W1Th COLUMNS is bad.
  // => retain dedicated W1 row-major planes, reconstructed here from W1Th? No.
  // (resolved in launcher: W1h/W1l row-major planes are still allocated and
  //  filled by k_prep2 below)
  (void)W1Th; (void)W1Tl; (void)hasBl; (void)xTl; (void)xTh; (void)bias;
  (void)xfh; (void)xfl; (void)hasxfl; (void)lAh; (void)lAl; (void)lBh; (void)lBl;
  (void)b; (void)m0; (void)n0; (void)wm; (void)wn; (void)quad; (void)l16;
}

// real conv1 (uses row-major W1 planes)
__global__ __launch_bounds__(256) void k_conv1r(const ushort_t* __restrict__ W1h,
    const ushort_t* __restrict__ W1l, const float* __restrict__ bias,
    const ushort_t* __restrict__ xTh, const ushort_t* __restrict__ xTl, int hasBl,
    ushort_t* __restrict__ xfh, ushort_t* __restrict__ xfl, int hasxfl){
  __shared__ __align__(16) ushort_t sm[4*128*64];
  ushort_t* lAh = sm;
  ushort_t* lAl = sm + 128*64;
  ushort_t* lBh = sm + 2*128*64;
  ushort_t* lBl = sm + 3*128*64;
  int b = blockIdx.z, m0 = blockIdx.y*128, n0 = blockIdx.x*128;
  int tid = threadIdx.x, wid = tid>>6, lane = tid&63, quad = lane>>4, l16 = lane&15;
  int wm = wid>>1, wn = wid&1;
  f32x4 zero4 = {0.f,0.f,0.f,0.f};
  f32x4 acc[4][4];
  #pragma unroll
  for (int i=0;i<4;++i){
    #pragma unroll
    for (int j=0;j<4;++j) acc[i][j] = zero4;
  }
  const ushort_t* Aph = W1h + (size_t)m0*CC;
  const ushort_t* Apl = W1l + (size_t)m0*CC;
  const ushort_t* Bph = xTh + ((size_t)b*NN + n0)*CC;
  const ushort_t* Bpl = hasBl ? xTl + ((size_t)b*NN + n0)*CC : nullptr;
  for (int k0 = 0; k0 < CC; k0 += 64){
    stage_lds<128>(Aph + k0, CC, lAh, tid);
    stage_lds<128>(Apl + k0, CC, lAl, tid);
    stage_lds<128>(Bph + k0, CC, lBh, tid);
    if (hasBl) stage_lds<128>(Bpl + k0, CC, lBl, tid);
    __syncthreads();
    #pragma unroll
    for (int kk = 0; kk < 64; kk += 32){
      bf16x8 ah[4], al[4], bh[4], bl[4];
      #pragma unroll
      for (int f=0; f<4; ++f){
        ah[f] = frag_ld(lAh, wm*64 + f*16 + l16, kk + quad*8);
        al[f] = frag_ld(lAl, wm*64 + f*16 + l16, kk + quad*8);
        bh[f] = frag_ld(lBh, wn*64 + f*16 + l16, kk + quad*8);
      }
      if (hasBl){
        #pragma unroll
        for (int f=0; f<4; ++f) bl[f] = frag_ld(lBl, wn*64 + f*16 + l16, kk + quad*8);
      }
      #pragma unroll
      for (int i=0;i<4;++i){
        #pragma unroll
        for (int j=0;j<4;++j){
          acc[i][j] = MFMA16(ah[i], bh[j], acc[i][j]);
          acc[i][j] = MFMA16(al[i], bh[j], acc[i][j]);
        }
      }
      if (hasBl){
        #pragma unroll
        for (int i=0;i<4;++i){
          #pragma unroll
          for (int j=0;j<4;++j) acc[i][j] = MFMA16(ah[i], bl[j], acc[i][j]);
        }
      }
    }
    __syncthreads();
  }
  // epilogue: add bias, hi plane then (optional) lo plane via LDS bounce, xf rows only
  ushort_t* ct = sm;   // 128 x pitch132
  float vals[4][4][4];
  #pragma unroll
  for (int i=0;i<4;++i){
    #pragma unroll
    for (int r=0;r<4;++r){
      int m = wm*64 + i*16 + quad*4 + r;
      float bv = bias[m0 + m];
      #pragma unroll
      for (int j=0;j<4;++j){
        float v = acc[i][j][r] + bv;
        vals[i][j][r] = v;
        ct[m*132 + (wn*64 + j*16 + l16)] = f2bu(v);
      }
    }
  }
  __syncthreads();
  {
    ushort_t* xfp = xfh + (size_t)b*CC*NN + (size_t)m0*NN + n0;
    #pragma unroll
    for (int i = 0; i < 16; ++i){
      int idx = tid + i*256;
      int m = idx >> 5, j4 = (idx & 31)*4;
      *(ushort4*)(xfp + (size_t)m*NN + j4) = *(ushort4*)(ct + m*132 + j4);
    }
  }
  if (hasxfl){
    __syncthreads();
    #pragma unroll
    for (int i=0;i<4;++i){
      #pragma unroll
      for (int r=0;r<4;++r){
        int m = wm*64 + i*16 + quad*4 + r;
        #pragma unroll
        for (int j=0;j<4;++j){
          float v = vals[i][j][r];
          ct[m*132 + (wn*64 + j*16 + l16)] = lo_part(v, f2bu(v));
        }
      }
    }
    __syncthreads();
    ushort_t* xfp = xfl + (size_t)b*CC*NN + (size_t)m0*NN + n0;
    #pragma unroll
    for (int i = 0; i < 16; ++i){
      int idx = tid + i*256;
      int m = idx >> 5, j4 = (idx & 31)*4;
      *(ushort4*)(xfp + (size_t)m*NN + j4) = *(ushort4*)(ct + m*132 + j4);
    }
  }
}

// ---------------- q[b][k] = sum_o b1[o]*m[o,k] ----------------
__global__ __launch_bounds__(256) void k_q(const float* __restrict__ b1f,
    const ushort_t* __restrict__ mTh, const ushort_t* __restrict__ mTl,
    float* __restrict__ qout){
  int b = blockIdx.x, t = threadIdx.x;
  int k = t & 63, seg = t >> 6;
  const ushort_t* mh = mTh + (size_t)b*KC*CC + (size_t)k*CC;
  const ushort_t* ml = mTl + (size_t)b*KC*CC + (size_t)k*CC;
  float s = 0.f;
  #pragma unroll 4
  for (int o = seg*128; o < seg*128 + 128; ++o)
    s += b1f[o]*(bu2f(mh[o]) + bu2f(ml[o]));
  __shared__ float red[256];
  red[t] = s; __syncthreads();
  if (seg == 0) qout[b*KC + k] = red[k] + red[64+k] + red[128+k] + red[192+k];
}

// ---------------- P^T[b][k][c] = (W1^T m)[c,k] hi/lo ----------------
__global__ __launch_bounds__(256) void k_wm(const ushort_t* __restrict__ W1Th,
    const ushort_t* __restrict__ W1Tl,
    const ushort_t* __restrict__ mTh, const ushort_t* __restrict__ mTl,
    ushort_t* __restrict__ PTh, ushort_t* __restrict__ PTl){
  __shared__ __align__(16) ushort_t sm[2*128*64 + 2*64*64];
  ushort_t* lAh = sm;
  ushort_t* lAl = sm + 128*64;
  ushort_t* lBh = sm + 2*128*64;
  ushort_t* lBl = sm + 2*128*64 + 64*64;
  int b = blockIdx.y, c0 = blockIdx.x*128;
  int tid = threadIdx.x, wid = tid>>6, lane = tid&63, quad = lane>>4, l16 = lane&15;
  f32x4 zero4 = {0.f,0.f,0.f,0.f};
  f32x4 acc[2][4];
  #pragma unroll
  for (int i=0;i<2;++i){
    #pragma unroll
    for (int j=0;j<4;++j) acc[i][j] = zero4;
  }
  const ushort_t* Aph = W1Th + (size_t)c0*CC;
  const ushort_t* Apl = W1Tl + (size_t)c0*CC;
  const ushort_t* Bph = mTh + (size_t)b*KC*CC;
  const ushort_t* Bpl = mTl + (size_t)b*KC*CC;
  for (int k0 = 0; k0 < CC; k0 += 64){
    stage_lds<128>(Aph + k0, CC, lAh, tid);
    stage_lds<128>(Apl + k0, CC, lAl, tid);
    stage_lds<64>(Bph + k0, CC, lBh, tid);
    stage_lds<64>(Bpl + k0, CC, lBl, tid);
    __syncthreads();
    #pragma unroll
    for (int kk = 0; kk < 64; kk += 32){
      bf16x8 ah[2], al[2], bh[4], bl[4];
      #pragma unroll
      for (int f=0; f<2; ++f){
        ah[f] = frag_ld(lAh, wid*32 + f*16 + l16, kk + quad*8);
        al[f] = frag_ld(lAl, wid*32 + f*16 + l16, kk + quad*8);
      }
      #pragma unroll
      for (int f=0; f<4; ++f){
        bh[f] = frag_ld(lBh, f*16 + l16, kk + quad*8);
        bl[f] = frag_ld(lBl, f*16 + l16, kk + quad*8);
      }
      #pragma unroll
      for (int i=0;i<2;++i){
        #pragma unroll
        for (int j=0;j<4;++j){
          acc[i][j] = MFMA16(ah[i], bh[j], acc[i][j]);
          acc[i][j] = MFMA16(ah[i], bl[j], acc[i][j]);
          acc[i][j] = MFMA16(al[i], bh[j], acc[i][j]);
        }
      }
    }
    __syncthreads();
  }
  // store P^T[k][c] hi/lo; c consecutive over r -> ushort4
  #pragma unroll
  for (int i=0;i<2;++i){
    int cbase = c0 + wid*32 + i*16 + quad*4;
    #pragma unroll
    for (int j=0;j<4;++j){
      int k = j*16 + l16;
      ushort4 vh, vl;
      float a0=acc[i][j][0], a1=acc[i][j][1], a2=acc[i][j][2], a3=acc[i][j][3];
      vh.x=f2bu(a0); vh.y=f2bu(a1); vh.z=f2bu(a2); vh.w=f2bu(a3);
      vl.x=lo_part(a0,vh.x); vl.y=lo_part(a1,vh.y); vl.z=lo_part(a2,vh.z); vl.w=lo_part(a3,vh.w);
      size_t off = ((size_t)b*KC + k)*CC + cbase;
      *(ushort4*)(PTh + off) = vh;
      *(ushort4*)(PTl + off) = vl;
    }
  }
}

// ---------------- logits(from xT,P) + softmax + colsum -> z, zT ----------------
__global__ __launch_bounds__(256) void k_logits(const ushort_t* __restrict__ xTh,
    const ushort_t* __restrict__ xTl, int hasAl,
    const ushort_t* __restrict__ PTh, const ushort_t* __restrict__ PTl,
    const float* __restrict__ q,
    ushort_t* __restrict__ zh, ushort_t* __restrict__ zl, int writeZ,
    ushort_t* __restrict__ zTh, ushort_t* __restrict__ zTl,
    float* __restrict__ colsum){
  __shared__ __align__(16) ushort_t sm[2*128*64 + 2*64*64];
  ushort_t* lAh = sm;
  ushort_t* lAl = sm + 128*64;
  ushort_t* lBh = sm + 2*128*64;
  ushort_t* lBl = sm + 2*128*64 + 64*64;
  int b = blockIdx.y, n0 = blockIdx.x*128;
  int tid = threadIdx.x, wid = tid>>6, lane = tid&63, quad = lane>>4, l16 = lane&15;
  f32x4 zero4 = {0.f,0.f,0.f,0.f};
  f32x4 acc[2][4];
  #pragma unroll
  for (int i=0;i<2;++i){
    #pragma unroll
    for (int j=0;j<4;++j) acc[i][j] = zero4;
  }
  const ushort_t* Aph = xTh + ((size_t)b*NN + n0)*CC;
  const ushort_t* Apl = hasAl ? xTl + ((size_t)b*NN + n0)*CC : nullptr;
  const ushort_t* Bph = PTh + (size_t)b*KC*CC;
  const ushort_t* Bpl = PTl + (size_t)b*KC*CC;
  for (int k0 = 0; k0 < CC; k0 += 64){
    stage_lds<128>(Aph + k0, CC, lAh, tid);
    if (hasAl) stage_lds<128>(Apl + k0, CC, lAl, tid);
    stage_lds<64>(Bph + k0, CC, lBh, tid);
    stage_lds<64>(Bpl + k0, CC, lBl, tid);
    __syncthreads();
    #pragma unroll
    for (int kk = 0; kk < 64; kk += 32){
      bf16x8 ah[2], al[2], bh[4], bl[4];
      #pragma unroll
      for (int f=0; f<2; ++f){
        ah[f] = frag_ld(lAh, wid*32 + f*16 + l16, kk + quad*8);
        if (hasAl) al[f] = frag_ld(lAl, wid*32 + f*16 + l16, kk + quad*8);
      }
      #pragma unroll
      for (int f=0; f<4; ++f){
        bh[f] = frag_ld(lBh, f*16 + l16, kk + quad*8);
        bl[f] = frag_ld(lBl, f*16 + l16, kk + quad*8);
      }
      #pragma unroll
      for (int i=0;i<2;++i){
        #pragma unroll
        for (int j=0;j<4;++j){
          acc[i][j] = MFMA16(ah[i], bh[j], acc[i][j]);
          acc[i][j] = MFMA16(ah[i], bl[j], acc[i][j]);
        }
      }
      if (hasAl){
        #pragma unroll
        for (int i=0;i<2;++i){
          #pragma unroll
          for (int j=0;j<4;++j) acc[i][j] = MFMA16(al[i], bh[j], acc[i][j]);
        }
      }
    }
    __syncthreads();
  }
  // + bias-term q[k], then softmax over 64 cols per row
  float qv[4];
  #pragma unroll
  for (int j=0;j<4;++j) qv[j] = q[b*KC + j*16 + l16];
  #pragma unroll
  for (int i=0;i<2;++i){
    #pragma unroll
    for (int r=0;r<4;++r){
      #pragma unroll
      for (int j=0;j<4;++j) acc[i][j][r] += qv[j];
      float mx = fmaxf(fmaxf(acc[i][0][r], acc[i][1][r]), fmaxf(acc[i][2][r], acc[i][3][r]));
      mx = fmaxf(mx, __shfl_xor(mx, 1));
      mx = fmaxf(mx, __shfl_xor(mx, 2));
      mx = fmaxf(mx, __shfl_xor(mx, 4));
      mx = fmaxf(mx, __shfl_xor(mx, 8));
      float e0 = __expf(acc[i][0][r]-mx), e1 = __expf(acc[i][1][r]-mx);
      float e2 = __expf(acc[i][2][r]-mx), e3 = __expf(acc[i][3][r]-mx);
      float s = e0+e1+e2+e3;
      s += __shfl_xor(s, 1); s += __shfl_xor(s, 2);
      s += __shfl_xor(s, 4); s += __shfl_xor(s, 8);
      float inv = 1.0f/s;
      acc[i][0][r] = e0*inv; acc[i][1][r] = e1*inv;
      acc[i][2][r] = e2*inv; acc[i][3][r] = e3*inv;
    }
  }
  // column sums -> atomics
  #pragma unroll
  for (int j=0;j<4;++j){
    float p = 0.f;
    #pragma unroll
    for (int i=0;i<2;++i){
      #pragma unroll
      for (int r=0;r<4;++r) p += acc[i][j][r];
    }
    p += __shfl_xor(p, 16); p += __shfl_xor(p, 32);
    if (lane < 16) atomicAdd(&colsum[b*KC + j*16 + l16], p);
  }
  // stores: zT always; z[n][k] planes only when needed (last iteration, for k_rec)
  #pragma unroll
  for (int i=0;i<2;++i){
    int nbase = wid*32 + i*16 + quad*4;
    #pragma unroll
    for (int j=0;j<4;++j){
      int k = j*16 + l16;
      ushort4 vh, vl;
      float a0=acc[i][j][0], a1=acc[i][j][1], a2=acc[i][j][2], a3=acc[i][j][3];
      vh.x=f2bu(a0); vh.y=f2bu(a1); vh.z=f2bu(a2); vh.w=f2bu(a3);
      vl.x=lo_part(a0,vh.x); vl.y=lo_part(a1,vh.y); vl.z=lo_part(a2,vh.z); vl.w=lo_part(a3,vh.w);
      size_t zoff = ((size_t)b*KC + k)*NN + n0 + nbase;
      *(ushort4*)(zTh + zoff) = vh;
      *(ushort4*)(zTl + zoff) = vl;
      if (writeZ){
        const ushort_t* ph = (const ushort_t*)&vh;
        const ushort_t* pl = (const ushort_t*)&vl;
        #pragma unroll
        for (int r=0;r<4;++r){
          size_t o = ((size_t)b*NN + n0 + nbase + r)*KC + k;
          zh[o] = ph[r]; zl[o] = pl[r];
        }
      }
    }
  }
}

// ---------------- m-GEMM split-K: m_part[s][b][k][c] = xf @ z_slice ----------------
__global__ __launch_bounds__(256) void k_mgemm(const ushort_t* __restrict__ xfh,
    const ushort_t* __restrict__ xfl, int hasAl,
    const ushort_t* __restrict__ zTh, const ushort_t* __restrict__ zTl,
    float* __restrict__ m_part){
  __shared__ __align__(16) ushort_t sm[2*128*64 + 2*64*64];
  ushort_t* lAh = sm;
  ushort_t* lAl = sm + 128*64;
  ushort_t* lBh = sm + 2*128*64;
  ushort_t* lBl = sm + 2*128*64 + 64*64;
  int c0 = blockIdx.x*128, slice = blockIdx.y, b = blockIdx.z;
  int tid = threadIdx.x, wid = tid>>6, lane = tid&63, quad = lane>>4, l16 = lane&15;
  f32x4 zero4 = {0.f,0.f,0.f,0.f};
  f32x4 acc[2][4];
  #pragma unroll
  for (int i=0;i<2;++i){
    #pragma unroll
    for (int j=0;j<4;++j) acc[i][j] = zero4;
  }
  const ushort_t* Aph = xfh + ((size_t)b*CC + c0)*NN + slice*512;
  const ushort_t* Apl = hasAl ? xfl + ((size_t)b*CC + c0)*NN + slice*512 : nullptr;
  const ushort_t* Bph = zTh + (size_t)b*KC*NN + slice*512;
  const ushort_t* Bpl = zTl + (size_t)b*KC*NN + slice*512;
  for (int k0 = 0; k0 < 512; k0 += 64){
    stage_lds<128>(Aph + k0, NN, lAh, tid);
    if (hasAl) stage_lds<128>(Apl + k0, NN, lAl, tid);
    stage_lds<64>(Bph + k0, NN, lBh, tid);
    stage_lds<64>(Bpl + k0, NN, lBl, tid);
    __syncthreads();
    #pragma unroll
    for (int kk = 0; kk < 64; kk += 32){
      bf16x8 ah[2], al[2], bh[4], bl[4];
      #pragma unroll
      for (int f=0; f<2; ++f){
        ah[f] = frag_ld(lAh, wid*32 + f*16 + l16, kk + quad*8);
        if (hasAl) al[f] = frag_ld(lAl, wid*32 + f*16 + l16, kk + quad*8);
      }
      #pragma unroll
      for (int f=0; f<4; ++f){
        bh[f] = frag_ld(lBh, f*16 + l16, kk + quad*8);
        bl[f] = frag_ld(lBl, f*16 + l16, kk + quad*8);
      }
      #pragma unroll
      for (int i=0;i<2;++i){
        #pragma unroll
        for (int j=0;j<4;++j){
          acc[i][j] = MFMA16(ah[i], bh[j], acc[i][j]);
          acc[i][j] = MFMA16(ah[i], bl[j], acc[i][j]);
        }
      }
      if (hasAl){
        #pragma unroll
        for (int i=0;i<2;++i){
          #pragma unroll
          for (int j=0;j<4;++j) acc[i][j] = MFMA16(al[i], bh[j], acc[i][j]);
        }
      }
    }
    __syncthreads();
  }
  #pragma unroll
  for (int i=0;i<2;++i){
    int c = c0 + wid*32 + i*16 + quad*4;
    #pragma unroll
    for (int j=0;j<4;++j){
      int k = j*16 + l16;
      *(f32x4*)(m_part + (((size_t)slice*BB + b)*KC + k)*CC + c) = acc[i][j];
    }
  }
}

// ---------------- reduce partials, colnorm, l2norm -> m planes ----------------
__global__ __launch_bounds__(256) void k_mnorm(const float* __restrict__ m_part,
    const float* __restrict__ colsum,
    ushort_t* __restrict__ mch, ushort_t* __restrict__ mcl,
    ushort_t* __restrict__ mTh, ushort_t* __restrict__ mTl){
  int k = blockIdx.x, b = blockIdx.y, t = threadIdx.x;
  float v0 = 0.f, v1 = 0.f;
  #pragma unroll
  for (int s = 0; s < 8; ++s){
    const float* p = m_part + (((size_t)s*BB + b)*KC + k)*CC;
    v0 += p[t]; v1 += p[t+256];
  }
  float sk = 1.0f/(1e-6f + colsum[b*KC + k]);
  v0 *= sk; v1 *= sk;
  float ss = v0*v0 + v1*v1;
  #pragma unroll
  for (int off = 1; off < 64; off <<= 1) ss += __shfl_xor(ss, off);
  __shared__ float red[4];
  if ((t&63) == 0) red[t>>6] = ss;
  __syncthreads();
  float inv = 1.0f/(1e-6f + sqrtf(red[0]+red[1]+red[2]+red[3]));
  v0 *= inv; v1 *= inv;
  ushort_t h0 = f2bu(v0), h1 = f2bu(v1);
  ushort_t l0 = lo_part(v0,h0), l1 = lo_part(v1,h1);
  size_t to = ((size_t)b*KC + k)*CC + t;
  mTh[to] = h0; mTh[to+256] = h1;
  mTl[to] = l0; mTl[to+256] = l1;
  size_t co = ((size_t)b*CC + t)*KC + k;
  mch[co] = h0; mch[co + (size_t)256*KC] = h1;
  mcl[co] = l0; mcl[co + (size_t)256*KC] = l1;
}

// ---------------- rec: recT[n][c] = relu(z @ m^T), hi/lo planes ----------------
__global__ __launch_bounds__(256) void k_rec(const ushort_t* __restrict__ zh,
    const ushort_t* __restrict__ zl,
    const ushort_t* __restrict__ mch, const ushort_t* __restrict__ mcl,
    ushort_t* __restrict__ recTh, ushort_t* __restrict__ recTl){
  __shared__ __align__(16) ushort_t sm[4*128*64];
  ushort_t* lAh = sm;
  ushort_t* lAl = sm + 128*64;
  ushort_t* lBh = sm + 2*128*64;
  ushort_t* lBl = sm + 3*128*64;
  int n0 = blockIdx.x*128, c0 = blockIdx.y*128, b = blockIdx.z;
  int tid = threadIdx.x, wid = tid>>6, lane = tid&63, quad = lane>>4, l16 = lane&15;
  int wm = wid>>1, wn = wid&1;
  f32x4 zero4 = {0.f,0.f,0.f,0.f};
  f32x4 acc[4][4];
  #pragma unroll
  for (int i=0;i<4;++i){
    #pragma unroll
    for (int j=0;j<4;++j) acc[i][j] = zero4;
  }
  stage_lds<128>(zh + ((size_t)b*NN + n0)*KC, KC, lAh, tid);
  stage_lds<128>(zl + ((size_t)b*NN + n0)*KC, KC, lAl, tid);
  stage_lds<128>(mch + ((size_t)b*CC + c0)*KC, KC, lBh, tid);
  stage_lds<128>(mcl + ((size_t)b*CC + c0)*KC, KC, lBl, tid);
  __syncthreads();
  #pragma unroll
  for (int kk = 0; kk < 64; kk += 32){
    bf16x8 ah[4], al[4], bh[4], bl[4];
    #pragma unroll
    for (int f=0; f<4; ++f){
      ah[f] = frag_ld(lAh, wm*64 + f*16 + l16, kk + quad*8);
      al[f] = frag_ld(lAl, wm*64 + f*16 + l16, kk + quad*8);
      bh[f] = frag_ld(lBh, wn*64 + f*16 + l16, kk + quad*8);
      bl[f] = frag_ld(lBl, wn*64 + f*16 + l16, kk + quad*8);
    }
    #pragma unroll
    for (int i=0;i<4;++i){
      #pragma unroll
      for (int j=0;j<4;++j){
        acc[i][j] = MFMA16(ah[i], bh[j], acc[i][j]);
        acc[i][j] = MFMA16(ah[i], bl[j], acc[i][j]);
        acc[i][j] = MFMA16(al[i], bh[j], acc[i][j]);
      }
    }
  }
  __syncthreads();
  ushort_t* ct = sm;
  // hi pass
  #pragma unroll
  for (int i=0;i<4;++i){
    #pragma unroll
    for (int r=0;r<4;++r){
      int m = wm*64 + i*16 + quad*4 + r;
      #pragma unroll
      for (int j=0;j<4;++j)
        ct[m*132 + (wn*64 + j*16 + l16)] = f2bu(fmaxf(acc[i][j][r], 0.f));
    }
  }
  __syncthreads();
  {
    ushort_t* rp = recTh + ((size_t)b*NN + n0)*CC + c0;
    #pragma unroll
    for (int i = 0; i < 16; ++i){
      int idx = tid + i*256;
      int m = idx >> 5, j4 = (idx & 31)*4;
      *(ushort4*)(rp + (size_t)m*CC + j4) = *(ushort4*)(ct + m*132 + j4);
    }
  }
  __syncthreads();
  // lo pass
  #pragma unroll
  for (int i=0;i<4;++i){
    #pragma unroll
    for (int r=0;r<4;++r){
      int m = wm*64 + i*16 + quad*4 + r;
      #pragma unroll
      for (int j=0;j<4;++j){
        float v = fmaxf(acc[i][j][r], 0.f);
        ct[m*132 + (wn*64 + j*16 + l16)] = lo_part(v, f2bu(v));
      }
    }
  }
  __syncthreads();
  {
    ushort_t* rp = recTl + ((size_t)b*NN + n0)*CC + c0;
    #pragma unroll
    for (int i = 0; i < 16; ++i){
      int idx = tid + i*256;
      int m = idx >> 5, j4 = (idx & 31)*4;
      *(ushort4*)(rp + (size_t)m*CC + j4) = *(ushort4*)(ct + m*132 + j4);
    }
  }
}

// ---------------- conv2 + BN -> out f32 [b][c][n] ----------------
__global__ __launch_bounds__(256) void k_conv2(const ushort_t* __restrict__ W2h,
    const ushort_t* __restrict__ W2l,
    const ushort_t* __restrict__ recTh, const ushort_t* __restrict__ recTl,
    const float* __restrict__ bnscale, const float* __restrict__ bnshift,
    float* __restrict__ out){
  __shared__ __align__(16) ushort_t sm[4*128*64];
  ushort_t* lAh = sm;
  ushort_t* lAl = sm + 128*64;
  ushort_t* lBh = sm + 2*128*64;
  ushort_t* lBl = sm + 3*128*64;
  int b = blockIdx.z, m0 = blockIdx.y*128, n0 = blockIdx.x*128;
  int tid = threadIdx.x, wid = tid>>6, lane = tid&63, quad = lane>>4, l16 = lane&15;
  int wm = wid>>1, wn = wid&1;
  f32x4 zero4 = {0.f,0.f,0.f,0.f};
  f32x4 acc[4][4];
  #pragma unroll
  for (int i=0;i<4;++i){
    #pragma unroll
    for (int j=0;j<4;++j) acc[i][j] = zero4;
  }
  const ushort_t* Aph = W2h + (size_t)m0*CC;
  const ushort_t* Apl = W2l + (size_t)m0*CC;
  const ushort_t* Bph = recTh + ((size_t)b*NN + n0)*CC;
  const ushort_t* Bpl = recTl + ((size_t)b*NN + n0)*CC;
  for (int k0 = 0; k0 < CC; k0 += 64){
    stage_lds<128>(Aph + k0, CC, lAh, tid);
    stage_lds<128>(Apl + k0, CC, lAl, tid);
    stage_lds<128>(Bph + k0, CC, lBh, tid);
    stage_lds<128>(Bpl + k0, CC, lBl, tid);
    __syncthreads();
    #pragma unroll
    for (int kk = 0; kk < 64; kk += 32){
      bf16x8 ah[4], al[4], bh[4], bl[4];
      #pragma unroll
      for (int f=0; f<4; ++f){
        ah[f] = frag_ld(lAh, wm*64 + f*16 + l16, kk + quad*8);
        al[f] = frag_ld(lAl, wm*64 + f*16 + l16, kk + quad*8);
        bh[f] = frag_ld(lBh, wn*64 + f*16 + l16, kk + quad*8);
        bl[f] = frag_ld(lBl, wn*64 + f*16 + l16, kk + quad*8);
      }
      #pragma unroll
      for (int i=0;i<4;++i){
        #pragma unroll
        for (int j=0;j<4;++j){
          acc[i][j] = MFMA16(ah[i], bh[j], acc[i][j]);
          acc[i][j] = MFMA16(ah[i], bl[j], acc[i][j]);
          acc[i][j] = MFMA16(al[i], bh[j], acc[i][j]);
        }
      }
    }
    __syncthreads();
  }
  size_t base = (size_t)b*CC*NN;
  #pragma unroll
  for (int i=0;i<4;++i){
    #pragma unroll
    for (int r=0;r<4;++r){
      int m = m0 + wm*64 + i*16 + quad*4 + r;
      float sc = bnscale[m], sh = bnshift[m];
      #pragma unroll
      for (int j=0;j<4;++j){
        int nn = n0 + wn*64 + j*16 + l16;
        out[base + (size_t)m*NN + nn] = acc[i][j][r]*sc + sh;
      }
    }
  }
}

// small helper: build row-major W1 hi/lo planes (for conv1) from W1 f32
__global__ __launch_bounds__(256) void k_prep2(const float* __restrict__ W1,
    ushort_t* __restrict__ W1h, ushort_t* __restrict__ W1l){
  int t = blockIdx.x*256 + threadIdx.x;
  if (t < CC*CC){
    float w1 = W1[t];
    ushort_t h1 = f2bu(w1);
    W1h[t] = h1; W1l[t] = lo_part(w1,h1);
  }
}

extern "C" void kernel_launch(void* const* d_in, const int* in_sizes, int n_in,
                              void* d_out, int out_size, void* d_ws, size_t ws_size,
                              hipStream_t stream) {
  (void)in_sizes; (void)n_in; (void)out_size;
  const float* x     = (const float*)d_in[0];
  const float* W1    = (const float*)d_in[1];
  const float* b1    = (const float*)d_in[2];
  const float* mu    = (const float*)d_in[3];
  const float* W2    = (const float*)d_in[4];
  const float* gamma = (const float*)d_in[5];
  const float* beta  = (const float*)d_in[6];
  const float* mean  = (const float*)d_in[7];
  const float* var   = (const float*)d_in[8];
  float* out = (float*)d_out;

  const size_t big = (size_t)BB*NN*CC*2;      // 64 MiB
  const size_t zsz = (size_t)BB*NN*KC*2;      // 8 MiB
  const size_t msz = (size_t)BB*KC*CC*2;      // 4 MiB
  char* w = (char*)d_ws;
  ushort_t* xTh  = (ushort_t*)w;  w += big;   // live until last k_logits
  ushort_t* xfh  = (ushort_t*)w;  w += big;   // live until last k_mgemm
  ushort_t* zh   = (ushort_t*)w;  w += zsz;
  ushort_t* zl   = (ushort_t*)w;  w += zsz;
  ushort_t* zTh  = (ushort_t*)w;  w += zsz;
  ushort_t* zTl  = (ushort_t*)w;  w += zsz;
  float*    m_part = (float*)w;   w += (size_t)8*BB*KC*CC*4;   // 16 MiB
  ushort_t* mTh  = (ushort_t*)w;  w += msz;
  ushort_t* mTl  = (ushort_t*)w;  w += msz;
  ushort_t* mch  = (ushort_t*)w;  w += msz;
  ushort_t* mcl  = (ushort_t*)w;  w += msz;
  ushort_t* PTh  = (ushort_t*)w;  w += msz;
  ushort_t* PTl  = (ushort_t*)w;  w += msz;
  ushort_t* W1h  = (ushort_t*)w;  w += (size_t)CC*CC*2;
  ushort_t* W1l  = (ushort_t*)w;  w += (size_t)CC*CC*2;
  ushort_t* W1Th = (ushort_t*)w;  w += (size_t)CC*CC*2;
  ushort_t* W1Tl = (ushort_t*)w;  w += (size_t)CC*CC*2;
  ushort_t* W2h  = (ushort_t*)w;  w += (size_t)CC*CC*2;
  ushort_t* W2l  = (ushort_t*)w;  w += (size_t)CC*CC*2;
  float*    bnscale = (float*)w;  w += 2048;
  float*    bnshift = (float*)w;  w += 2048;
  float*    b1f  = (float*)w;     w += 2048;
  float*    colsum = (float*)w;   w += (size_t)BB*KC*4;
  float*    qbuf = (float*)w;     w += (size_t)BB*KC*4;
  // optional lo planes
  ushort_t* xTl = nullptr; ushort_t* xfl = nullptr;
  size_t used = (size_t)(w - (char*)d_ws);
  if (used + big <= ws_size){ xTl = (ushort_t*)w; w += big; used += big; }
  if (used + big <= ws_size){ xfl = (ushort_t*)w; w += big; used += big; }
  int hasxTl = xTl != nullptr, hasxfl = xfl != nullptr;
  // rec outputs reuse buffers dead by then: xfh (after last mgemm), xTh (after last logits)
  ushort_t* recTh = xfh;
  ushort_t* recTl = xTh;

  k_transpose<<<dim3(NN/64, CC/64, BB), 256, 0, stream>>>(x, xTh, xTl, hasxTl);
  k_prep<<<dim3((BB*KC*CC + 255)/256), 256, 0, stream>>>(gamma, beta, mean, var, b1,
      W1, W2, mu, bnscale, bnshift, b1f, W1Th, W1Tl, W2h, W2l, mTh, mTl);
  k_prep2<<<dim3((CC*CC + 255)/256), 256, 0, stream>>>(W1, W1h, W1l);
  k_conv1r<<<dim3(NN/128, CC/128, BB), 256, 0, stream>>>(W1h, W1l, b1f, xTh, xTl, hasxTl,
      xfh, xfl, hasxfl);
  for (int it = 0; it < 3; ++it){
    (void)hipMemsetAsync(colsum, 0, (size_t)BB*KC*4, stream);
    k_q<<<dim3(BB), 256, 0, stream>>>(b1f, mTh, mTl, qbuf);
    k_wm<<<dim3(CC/128, BB), 256, 0, stream>>>(W1Th, W1Tl, mTh, mTl, PTh, PTl);
    k_logits<<<dim3(NN/128, BB), 256, 0, stream>>>(xTh, xTl, hasxTl, PTh, PTl, qbuf,
        zh, zl, (it == 2) ? 1 : 0, zTh, zTl, colsum);
    k_mgemm<<<dim3(CC/128, 8, BB), 256, 0, stream>>>(xfh, xfl, hasxfl, zTh, zTl, m_part);
    k_mnorm<<<dim3(KC, BB), 256, 0, stream>>>(m_part, colsum, mch, mcl, mTh, mTl);
  }
  k_rec<<<dim3(NN/128, CC/128, BB), 256, 0, stream>>>(zh, zl, mch, mcl, recTh, recTl);
  k_conv2<<<dim3(NN/128, CC/128, BB), 256, 0, stream>>>(W2h, W2l, recTh, recTl,
      bnscale, bnshift, out);
}

// Round 6
// 806.188 us; speedup vs baseline: 1.0273x; 1.0273x over previous
//
#include <hip/hip_runtime.h>
#include <stdint.h>

#define BB 16
#define CC 512
#define NN 4096
#define KC 64

typedef unsigned short ushort_t;
typedef __attribute__((ext_vector_type(8))) __bf16 bf16x8;
typedef __attribute__((ext_vector_type(4))) float f32x4;

static __device__ __forceinline__ float bu2f(ushort_t u){
  union{unsigned int i; float f;} v; v.i = ((unsigned int)u)<<16; return v.f;
}
static __device__ __forceinline__ ushort_t f2bu(float f){
  unsigned int x = __float_as_uint(f);
  return (ushort_t)((x + 0x7FFFu + ((x>>16)&1u)) >> 16);
}
static __device__ __forceinline__ ushort_t lo_part(float v, ushort_t hi){
  return f2bu(v - bu2f(hi));
}

#define MFMA16(a,b,c) __builtin_amdgcn_mfma_f32_16x16x32_bf16(a,b,c,0,0,0)

// ---- staging: ROWS x 64 bf16 tile, global (row-major, ld elems) -> LDS ----
// LDS layout: linear 128B rows (pitch 64 elems), 16B segments XOR-swizzled:
//   LDS[row][s] holds global[row][s ^ (row&7)]  (s = 16B segment index 0..7)
// Loaded via global_load_lds(16B): dest is wave-uniform base + lane*16B, so
// the swizzle is applied on the per-lane GLOBAL source address (m173/m201).
template<int ROWS>
static __device__ __forceinline__ void stage_lds(const ushort_t* __restrict__ g, int ld,
                                                 ushort_t* l, int tid){
  int wid = tid >> 6, lane = tid & 63;
  #pragma unroll
  for (int it = 0; it < ROWS/32; ++it){
    int chunk = it*4 + wid;              // 1024B (8 rows) per wave-instruction
    int row = chunk*8 + (lane >> 3);
    int seg = (lane & 7) ^ (row & 7);    // pre-swizzled source segment
    const ushort_t* gp = g + (size_t)row*ld + seg*8;
    ushort_t* lp = l + chunk*512;        // wave-uniform; HW adds lane*16B
    __builtin_amdgcn_global_load_lds(
        (const __attribute__((address_space(1))) void*)gp,
        (__attribute__((address_space(3))) void*)lp, 16, 0, 0);
  }
}
// fragment read applies the same XOR involution (ko is a multiple of 8)
static __device__ __forceinline__ bf16x8 frag_ld(const ushort_t* l, int row, int ko){
  return *(const bf16x8*)(l + row*64 + (ko ^ ((row & 7) << 3)));
}

// ---------------- transpose x[b][c][n] (f32) -> xT planes [b][n][c] (bf16 hi/lo) ----------------
__global__ __launch_bounds__(256) void k_transpose(const float* __restrict__ x,
    ushort_t* __restrict__ xTh, ushort_t* __restrict__ xTl, int hasLo){
  __shared__ ushort_t th[64][68];
  __shared__ ushort_t tl[64][68];
  int b = blockIdx.z, c0 = blockIdx.y*64, n0 = blockIdx.x*64;
  int r16 = threadIdx.x >> 4;
  int q4  = (threadIdx.x & 15) * 4;
  #pragma unroll
  for (int p = 0; p < 4; ++p){
    int row = r16 + p*16;   // c index within tile
    size_t off = ((size_t)b*CC + c0 + row)*NN + n0 + q4;
    float4 v = *(const float4*)(x + off);
    ushort_t h0=f2bu(v.x), h1=f2bu(v.y), h2=f2bu(v.z), h3=f2bu(v.w);
    th[q4+0][row]=h0; th[q4+1][row]=h1; th[q4+2][row]=h2; th[q4+3][row]=h3;
    if (hasLo){
      tl[q4+0][row]=lo_part(v.x,h0); tl[q4+1][row]=lo_part(v.y,h1);
      tl[q4+2][row]=lo_part(v.z,h2); tl[q4+3][row]=lo_part(v.w,h3);
    }
  }
  __syncthreads();
  #pragma unroll
  for (int p = 0; p < 4; ++p){
    int nrow = r16 + p*16;
    size_t off = ((size_t)b*NN + n0 + nrow)*CC + c0 + q4;
    ushort4 v;
    v.x = th[nrow][q4+0]; v.y = th[nrow][q4+1]; v.z = th[nrow][q4+2]; v.w = th[nrow][q4+3];
    *(ushort4*)(xTh + off) = v;
    if (hasLo){
      ushort4 u;
      u.x = tl[nrow][q4+0]; u.y = tl[nrow][q4+1]; u.z = tl[nrow][q4+2]; u.w = tl[nrow][q4+3];
      *(ushort4*)(xTl + off) = u;
    }
  }
}

// ---------------- prep: W1 (row-major + transposed) hi-lo, W2 hi-lo, mu->mT hi-lo, BN, bias ----------------
__global__ __launch_bounds__(256) void k_prep(const float* __restrict__ gamma,
    const float* __restrict__ beta, const float* __restrict__ mean,
    const float* __restrict__ var, const float* __restrict__ b1,
    const float* __restrict__ W1, const float* __restrict__ W2,
    const float* __restrict__ mu,
    float* __restrict__ bnscale, float* __restrict__ bnshift,
    float* __restrict__ b1f,
    ushort_t* __restrict__ W1h, ushort_t* __restrict__ W1l,
    ushort_t* __restrict__ W1Th, ushort_t* __restrict__ W1Tl,
    ushort_t* __restrict__ W2h, ushort_t* __restrict__ W2l,
    ushort_t* __restrict__ mTh, ushort_t* __restrict__ mTl){
  int t = blockIdx.x*256 + threadIdx.x;
  if (t < CC){
    float inv = gamma[t] * rsqrtf(var[t] + 1e-5f);
    bnscale[t] = inv;
    bnshift[t] = beta[t] - mean[t]*inv;
    b1f[t] = b1[t];
  }
  if (t < CC*CC){
    int o = t >> 9, c = t & (CC-1);
    float w1 = W1[t], w2 = W2[t];
    ushort_t h1 = f2bu(w1), h2 = f2bu(w2);
    W1h[t] = h1; W1l[t] = lo_part(w1,h1);
    W1Th[(size_t)c*CC + o] = h1; W1Tl[(size_t)c*CC + o] = lo_part(w1,h1);
    W2h[t] = h2; W2l[t] = lo_part(w2,h2);
  }
  if (t < BB*KC*CC){
    int c = t & (CC-1);
    int k = (t >> 9) & (KC-1);
    float v = mu[(size_t)c*KC + k];
    ushort_t h = f2bu(v);
    mTh[t] = h; mTl[t] = lo_part(v,h);
  }
}

// ---------------- conv1: x1 = W1 @ x + b -> xf[c][n] only (hi/lo planes) ----------------
__global__ __launch_bounds__(256) void k_conv1r(const ushort_t* __restrict__ W1h,
    const ushort_t* __restrict__ W1l, const float* __restrict__ bias,
    const ushort_t* __restrict__ xTh, const ushort_t* __restrict__ xTl, int hasBl,
    ushort_t* __restrict__ xfh, ushort_t* __restrict__ xfl, int hasxfl){
  __shared__ __align__(16) ushort_t sm[4*128*64];
  ushort_t* lAh = sm;
  ushort_t* lAl = sm + 128*64;
  ushort_t* lBh = sm + 2*128*64;
  ushort_t* lBl = sm + 3*128*64;
  int b = blockIdx.z, m0 = blockIdx.y*128, n0 = blockIdx.x*128;
  int tid = threadIdx.x, wid = tid>>6, lane = tid&63, quad = lane>>4, l16 = lane&15;
  int wm = wid>>1, wn = wid&1;
  f32x4 zero4 = {0.f,0.f,0.f,0.f};
  f32x4 acc[4][4];
  #pragma unroll
  for (int i=0;i<4;++i){
    #pragma unroll
    for (int j=0;j<4;++j) acc[i][j] = zero4;
  }
  const ushort_t* Aph = W1h + (size_t)m0*CC;
  const ushort_t* Apl = W1l + (size_t)m0*CC;
  const ushort_t* Bph = xTh + ((size_t)b*NN + n0)*CC;
  const ushort_t* Bpl = hasBl ? xTl + ((size_t)b*NN + n0)*CC : nullptr;
  for (int k0 = 0; k0 < CC; k0 += 64){
    stage_lds<128>(Aph + k0, CC, lAh, tid);
    stage_lds<128>(Apl + k0, CC, lAl, tid);
    stage_lds<128>(Bph + k0, CC, lBh, tid);
    if (hasBl) stage_lds<128>(Bpl + k0, CC, lBl, tid);
    __syncthreads();
    #pragma unroll
    for (int kk = 0; kk < 64; kk += 32){
      bf16x8 ah[4], al[4], bh[4], bl[4];
      #pragma unroll
      for (int f=0; f<4; ++f){
        ah[f] = frag_ld(lAh, wm*64 + f*16 + l16, kk + quad*8);
        al[f] = frag_ld(lAl, wm*64 + f*16 + l16, kk + quad*8);
        bh[f] = frag_ld(lBh, wn*64 + f*16 + l16, kk + quad*8);
      }
      if (hasBl){
        #pragma unroll
        for (int f=0; f<4; ++f) bl[f] = frag_ld(lBl, wn*64 + f*16 + l16, kk + quad*8);
      }
      #pragma unroll
      for (int i=0;i<4;++i){
        #pragma unroll
        for (int j=0;j<4;++j){
          acc[i][j] = MFMA16(ah[i], bh[j], acc[i][j]);
          acc[i][j] = MFMA16(al[i], bh[j], acc[i][j]);
        }
      }
      if (hasBl){
        #pragma unroll
        for (int i=0;i<4;++i){
          #pragma unroll
          for (int j=0;j<4;++j) acc[i][j] = MFMA16(ah[i], bl[j], acc[i][j]);
        }
      }
    }
    __syncthreads();
  }
  // epilogue: add bias, hi plane then (optional) lo plane via LDS bounce, xf rows only
  ushort_t* ct = sm;   // 128 x pitch132
  float vals[4][4][4];
  #pragma unroll
  for (int i=0;i<4;++i){
    #pragma unroll
    for (int r=0;r<4;++r){
      int m = wm*64 + i*16 + quad*4 + r;
      float bv = bias[m0 + m];
      #pragma unroll
      for (int j=0;j<4;++j){
        float v = acc[i][j][r] + bv;
        vals[i][j][r] = v;
        ct[m*132 + (wn*64 + j*16 + l16)] = f2bu(v);
      }
    }
  }
  __syncthreads();
  {
    ushort_t* xfp = xfh + (size_t)b*CC*NN + (size_t)m0*NN + n0;
    #pragma unroll
    for (int i = 0; i < 16; ++i){
      int idx = tid + i*256;
      int m = idx >> 5, j4 = (idx & 31)*4;
      *(ushort4*)(xfp + (size_t)m*NN + j4) = *(ushort4*)(ct + m*132 + j4);
    }
  }
  if (hasxfl){
    __syncthreads();
    #pragma unroll
    for (int i=0;i<4;++i){
      #pragma unroll
      for (int r=0;r<4;++r){
        int m = wm*64 + i*16 + quad*4 + r;
        #pragma unroll
        for (int j=0;j<4;++j){
          float v = vals[i][j][r];
          ct[m*132 + (wn*64 + j*16 + l16)] = lo_part(v, f2bu(v));
        }
      }
    }
    __syncthreads();
    ushort_t* xfp = xfl + (size_t)b*CC*NN + (size_t)m0*NN + n0;
    #pragma unroll
    for (int i = 0; i < 16; ++i){
      int idx = tid + i*256;
      int m = idx >> 5, j4 = (idx & 31)*4;
      *(ushort4*)(xfp + (size_t)m*NN + j4) = *(ushort4*)(ct + m*132 + j4);
    }
  }
}

// ---------------- q[b][k] = sum_o b1[o]*m[o,k]  (iteration 0 only) ----------------
__global__ __launch_bounds__(256) void k_q(const float* __restrict__ b1f,
    const ushort_t* __restrict__ mTh, const ushort_t* __restrict__ mTl,
    float* __restrict__ qout){
  int b = blockIdx.x, t = threadIdx.x;
  int k = t & 63, seg = t >> 6;
  const ushort_t* mh = mTh + (size_t)b*KC*CC + (size_t)k*CC;
  const ushort_t* ml = mTl + (size_t)b*KC*CC + (size_t)k*CC;
  float s = 0.f;
  #pragma unroll 4
  for (int o = seg*128; o < seg*128 + 128; ++o)
    s += b1f[o]*(bu2f(mh[o]) + bu2f(ml[o]));
  __shared__ float red[256];
  red[t] = s; __syncthreads();
  if (seg == 0) qout[b*KC + k] = red[k] + red[64+k] + red[128+k] + red[192+k];
}

// ---------------- P^T: one batched GEMM over the flat [1024][512] m matrix ----------------
// D[c][bk] = sum_o W1T[c][o] * m_flat[bk][o];  store PT[bk][c] (c contiguous over r)
__global__ __launch_bounds__(256) void k_wm2(const ushort_t* __restrict__ W1Th,
    const ushort_t* __restrict__ W1Tl,
    const ushort_t* __restrict__ mTh, const ushort_t* __restrict__ mTl,
    ushort_t* __restrict__ PTh, ushort_t* __restrict__ PTl){
  __shared__ __align__(16) ushort_t sm[4*64*64];   // 32 KiB
  ushort_t* lAh = sm;
  ushort_t* lAl = sm + 4096;
  ushort_t* lBh = sm + 8192;
  ushort_t* lBl = sm + 12288;
  int c0 = blockIdx.x*64, bk0 = blockIdx.y*64;
  int tid = threadIdx.x, wid = tid>>6, lane = tid&63, quad = lane>>4, l16 = lane&15;
  f32x4 zero4 = {0.f,0.f,0.f,0.f};
  f32x4 acc[4];
  #pragma unroll
  for (int j=0;j<4;++j) acc[j] = zero4;
  const ushort_t* Aph = W1Th + (size_t)c0*CC;
  const ushort_t* Apl = W1Tl + (size_t)c0*CC;
  const ushort_t* Bph = mTh + (size_t)bk0*CC;   // m flat [1024][512]
  const ushort_t* Bpl = mTl + (size_t)bk0*CC;
  for (int k0 = 0; k0 < CC; k0 += 64){
    stage_lds<64>(Aph + k0, CC, lAh, tid);
    stage_lds<64>(Apl + k0, CC, lAl, tid);
    stage_lds<64>(Bph + k0, CC, lBh, tid);
    stage_lds<64>(Bpl + k0, CC, lBl, tid);
    __syncthreads();
    #pragma unroll
    for (int kk = 0; kk < 64; kk += 32){
      bf16x8 ah, al, bh[4], bl[4];
      ah = frag_ld(lAh, wid*16 + l16, kk + quad*8);
      al = frag_ld(lAl, wid*16 + l16, kk + quad*8);
      #pragma unroll
      for (int f=0; f<4; ++f){
        bh[f] = frag_ld(lBh, f*16 + l16, kk + quad*8);
        bl[f] = frag_ld(lBl, f*16 + l16, kk + quad*8);
      }
      #pragma unroll
      for (int j=0;j<4;++j){
        acc[j] = MFMA16(ah, bh[j], acc[j]);
        acc[j] = MFMA16(ah, bl[j], acc[j]);
        acc[j] = MFMA16(al, bh[j], acc[j]);
      }
    }
    __syncthreads();
  }
  int cbase = c0 + wid*16 + quad*4;
  #pragma unroll
  for (int j=0;j<4;++j){
    int bk = bk0 + j*16 + l16;
    ushort4 vh, vl;
    float a0=acc[j][0], a1=acc[j][1], a2=acc[j][2], a3=acc[j][3];
    vh.x=f2bu(a0); vh.y=f2bu(a1); vh.z=f2bu(a2); vh.w=f2bu(a3);
    vl.x=lo_part(a0,vh.x); vl.y=lo_part(a1,vh.y); vl.z=lo_part(a2,vh.z); vl.w=lo_part(a3,vh.w);
    size_t off = (size_t)bk*CC + cbase;
    *(ushort4*)(PTh + off) = vh;
    *(ushort4*)(PTl + off) = vl;
  }
}

// ---------------- logits(from xT,P) + softmax + colsum -> z, zT ----------------
__global__ __launch_bounds__(256) void k_logits(const ushort_t* __restrict__ xTh,
    const ushort_t* __restrict__ xTl, int hasAl,
    const ushort_t* __restrict__ PTh, const ushort_t* __restrict__ PTl,
    const float* __restrict__ q,
    ushort_t* __restrict__ zh, ushort_t* __restrict__ zl, int writeZ,
    ushort_t* __restrict__ zTh, ushort_t* __restrict__ zTl,
    float* __restrict__ colsum){
  __shared__ __align__(16) ushort_t sm[2*128*64 + 2*64*64];
  ushort_t* lAh = sm;
  ushort_t* lAl = sm + 128*64;
  ushort_t* lBh = sm + 2*128*64;
  ushort_t* lBl = sm + 2*128*64 + 64*64;
  int b = blockIdx.y, n0 = blockIdx.x*128;
  int tid = threadIdx.x, wid = tid>>6, lane = tid&63, quad = lane>>4, l16 = lane&15;
  f32x4 zero4 = {0.f,0.f,0.f,0.f};
  f32x4 acc[2][4];
  #pragma unroll
  for (int i=0;i<2;++i){
    #pragma unroll
    for (int j=0;j<4;++j) acc[i][j] = zero4;
  }
  const ushort_t* Aph = xTh + ((size_t)b*NN + n0)*CC;
  const ushort_t* Apl = hasAl ? xTl + ((size_t)b*NN + n0)*CC : nullptr;
  const ushort_t* Bph = PTh + (size_t)b*KC*CC;
  const ushort_t* Bpl = PTl + (size_t)b*KC*CC;
  for (int k0 = 0; k0 < CC; k0 += 64){
    stage_lds<128>(Aph + k0, CC, lAh, tid);
    if (hasAl) stage_lds<128>(Apl + k0, CC, lAl, tid);
    stage_lds<64>(Bph + k0, CC, lBh, tid);
    stage_lds<64>(Bpl + k0, CC, lBl, tid);
    __syncthreads();
    #pragma unroll
    for (int kk = 0; kk < 64; kk += 32){
      bf16x8 ah[2], al[2], bh[4], bl[4];
      #pragma unroll
      for (int f=0; f<2; ++f){
        ah[f] = frag_ld(lAh, wid*32 + f*16 + l16, kk + quad*8);
        if (hasAl) al[f] = frag_ld(lAl, wid*32 + f*16 + l16, kk + quad*8);
      }
      #pragma unroll
      for (int f=0; f<4; ++f){
        bh[f] = frag_ld(lBh, f*16 + l16, kk + quad*8);
        bl[f] = frag_ld(lBl, f*16 + l16, kk + quad*8);
      }
      #pragma unroll
      for (int i=0;i<2;++i){
        #pragma unroll
        for (int j=0;j<4;++j){
          acc[i][j] = MFMA16(ah[i], bh[j], acc[i][j]);
          acc[i][j] = MFMA16(ah[i], bl[j], acc[i][j]);
        }
      }
      if (hasAl){
        #pragma unroll
        for (int i=0;i<2;++i){
          #pragma unroll
          for (int j=0;j<4;++j) acc[i][j] = MFMA16(al[i], bh[j], acc[i][j]);
        }
      }
    }
    __syncthreads();
  }
  // + bias-term q[k], then softmax over 64 cols per row
  float qv[4];
  #pragma unroll
  for (int j=0;j<4;++j) qv[j] = q[b*KC + j*16 + l16];
  #pragma unroll
  for (int i=0;i<2;++i){
    #pragma unroll
    for (int r=0;r<4;++r){
      #pragma unroll
      for (int j=0;j<4;++j) acc[i][j][r] += qv[j];
      float mx = fmaxf(fmaxf(acc[i][0][r], acc[i][1][r]), fmaxf(acc[i][2][r], acc[i][3][r]));
      mx = fmaxf(mx, __shfl_xor(mx, 1));
      mx = fmaxf(mx, __shfl_xor(mx, 2));
      mx = fmaxf(mx, __shfl_xor(mx, 4));
      mx = fmaxf(mx, __shfl_xor(mx, 8));
      float e0 = __expf(acc[i][0][r]-mx), e1 = __expf(acc[i][1][r]-mx);
      float e2 = __expf(acc[i][2][r]-mx), e3 = __expf(acc[i][3][r]-mx);
      float s = e0+e1+e2+e3;
      s += __shfl_xor(s, 1); s += __shfl_xor(s, 2);
      s += __shfl_xor(s, 4); s += __shfl_xor(s, 8);
      float inv = 1.0f/s;
      acc[i][0][r] = e0*inv; acc[i][1][r] = e1*inv;
      acc[i][2][r] = e2*inv; acc[i][3][r] = e3*inv;
    }
  }
  // column sums -> atomics
  #pragma unroll
  for (int j=0;j<4;++j){
    float p = 0.f;
    #pragma unroll
    for (int i=0;i<2;++i){
      #pragma unroll
      for (int r=0;r<4;++r) p += acc[i][j][r];
    }
    p += __shfl_xor(p, 16); p += __shfl_xor(p, 32);
    if (lane < 16) atomicAdd(&colsum[b*KC + j*16 + l16], p);
  }
  // stores: zT always; z[n][k] planes only last iteration (for k_rec)
  #pragma unroll
  for (int i=0;i<2;++i){
    int nbase = wid*32 + i*16 + quad*4;
    #pragma unroll
    for (int j=0;j<4;++j){
      int k = j*16 + l16;
      ushort4 vh, vl;
      float a0=acc[i][j][0], a1=acc[i][j][1], a2=acc[i][j][2], a3=acc[i][j][3];
      vh.x=f2bu(a0); vh.y=f2bu(a1); vh.z=f2bu(a2); vh.w=f2bu(a3);
      vl.x=lo_part(a0,vh.x); vl.y=lo_part(a1,vh.y); vl.z=lo_part(a2,vh.z); vl.w=lo_part(a3,vh.w);
      size_t zoff = ((size_t)b*KC + k)*NN + n0 + nbase;
      *(ushort4*)(zTh + zoff) = vh;
      *(ushort4*)(zTl + zoff) = vl;
      if (writeZ){
        const ushort_t* ph = (const ushort_t*)&vh;
        const ushort_t* pl = (const ushort_t*)&vl;
        #pragma unroll
        for (int r=0;r<4;++r){
          size_t o = ((size_t)b*NN + n0 + nbase + r)*KC + k;
          zh[o] = ph[r]; zl[o] = pl[r];
        }
      }
    }
  }
}

// ---------------- m-GEMM split-K: m_part[s][b][k][c] = xf @ z_slice ----------------
__global__ __launch_bounds__(256) void k_mgemm(const ushort_t* __restrict__ xfh,
    const ushort_t* __restrict__ xfl, int hasAl,
    const ushort_t* __restrict__ zTh, const ushort_t* __restrict__ zTl,
    float* __restrict__ m_part){
  __shared__ __align__(16) ushort_t sm[2*128*64 + 2*64*64];
  ushort_t* lAh = sm;
  ushort_t* lAl = sm + 128*64;
  ushort_t* lBh = sm + 2*128*64;
  ushort_t* lBl = sm + 2*128*64 + 64*64;
  int c0 = blockIdx.x*128, slice = blockIdx.y, b = blockIdx.z;
  int tid = threadIdx.x, wid = tid>>6, lane = tid&63, quad = lane>>4, l16 = lane&15;
  f32x4 zero4 = {0.f,0.f,0.f,0.f};
  f32x4 acc[2][4];
  #pragma unroll
  for (int i=0;i<2;++i){
    #pragma unroll
    for (int j=0;j<4;++j) acc[i][j] = zero4;
  }
  const ushort_t* Aph = xfh + ((size_t)b*CC + c0)*NN + slice*512;
  const ushort_t* Apl = hasAl ? xfl + ((size_t)b*CC + c0)*NN + slice*512 : nullptr;
  const ushort_t* Bph = zTh + (size_t)b*KC*NN + slice*512;
  const ushort_t* Bpl = zTl + (size_t)b*KC*NN + slice*512;
  for (int k0 = 0; k0 < 512; k0 += 64){
    stage_lds<128>(Aph + k0, NN, lAh, tid);
    if (hasAl) stage_lds<128>(Apl + k0, NN, lAl, tid);
    stage_lds<64>(Bph + k0, NN, lBh, tid);
    stage_lds<64>(Bpl + k0, NN, lBl, tid);
    __syncthreads();
    #pragma unroll
    for (int kk = 0; kk < 64; kk += 32){
      bf16x8 ah[2], al[2], bh[4], bl[4];
      #pragma unroll
      for (int f=0; f<2; ++f){
        ah[f] = frag_ld(lAh, wid*32 + f*16 + l16, kk + quad*8);
        if (hasAl) al[f] = frag_ld(lAl, wid*32 + f*16 + l16, kk + quad*8);
      }
      #pragma unroll
      for (int f=0; f<4; ++f){
        bh[f] = frag_ld(lBh, f*16 + l16, kk + quad*8);
        bl[f] = frag_ld(lBl, f*16 + l16, kk + quad*8);
      }
      #pragma unroll
      for (int i=0;i<2;++i){
        #pragma unroll
        for (int j=0;j<4;++j){
          acc[i][j] = MFMA16(ah[i], bh[j], acc[i][j]);
          acc[i][j] = MFMA16(ah[i], bl[j], acc[i][j]);
        }
      }
      if (hasAl){
        #pragma unroll
        for (int i=0;i<2;++i){
          #pragma unroll
          for (int j=0;j<4;++j) acc[i][j] = MFMA16(al[i], bh[j], acc[i][j]);
        }
      }
    }
    __syncthreads();
  }
  #pragma unroll
  for (int i=0;i<2;++i){
    int c = c0 + wid*32 + i*16 + quad*4;
    #pragma unroll
    for (int j=0;j<4;++j){
      int k = j*16 + l16;
      *(f32x4*)(m_part + (((size_t)slice*BB + b)*KC + k)*CC + c) = acc[i][j];
    }
  }
}

// ---------------- reduce partials, colnorm, l2norm -> m planes; also q for next iter ----------------
__global__ __launch_bounds__(256) void k_mnorm(const float* __restrict__ m_part,
    const float* __restrict__ colsum, const float* __restrict__ b1f,
    ushort_t* __restrict__ mch, ushort_t* __restrict__ mcl,
    ushort_t* __restrict__ mTh, ushort_t* __restrict__ mTl,
    float* __restrict__ qout){
  int k = blockIdx.x, b = blockIdx.y, t = threadIdx.x;
  float v0 = 0.f, v1 = 0.f;
  #pragma unroll
  for (int s = 0; s < 8; ++s){
    const float* p = m_part + (((size_t)s*BB + b)*KC + k)*CC;
    v0 += p[t]; v1 += p[t+256];
  }
  float sk = 1.0f/(1e-6f + colsum[b*KC + k]);
  v0 *= sk; v1 *= sk;
  float ss = v0*v0 + v1*v1;
  #pragma unroll
  for (int off = 1; off < 64; off <<= 1) ss += __shfl_xor(ss, off);
  __shared__ float red[4];
  if ((t&63) == 0) red[t>>6] = ss;
  __syncthreads();
  float inv = 1.0f/(1e-6f + sqrtf(red[0]+red[1]+red[2]+red[3]));
  v0 *= inv; v1 *= inv;
  ushort_t h0 = f2bu(v0), h1 = f2bu(v1);
  ushort_t l0 = lo_part(v0,h0), l1 = lo_part(v1,h1);
  size_t to = ((size_t)b*KC + k)*CC + t;
  mTh[to] = h0; mTh[to+256] = h1;
  mTl[to] = l0; mTl[to+256] = l1;
  size_t co = ((size_t)b*CC + t)*KC + k;
  mch[co] = h0; mch[co + (size_t)256*KC] = h1;
  mcl[co] = l0; mcl[co + (size_t)256*KC] = l1;
  // q for next iteration: sum_o b1[o] * m_rounded[o][k]
  float qs = b1f[t]*(bu2f(h0)+bu2f(l0)) + b1f[t+256]*(bu2f(h1)+bu2f(l1));
  #pragma unroll
  for (int off = 1; off < 64; off <<= 1) qs += __shfl_xor(qs, off);
  __shared__ float red2[4];
  __syncthreads();
  if ((t&63) == 0) red2[t>>6] = qs;
  __syncthreads();
  if (t == 0) qout[b*KC + k] = red2[0]+red2[1]+red2[2]+red2[3];
}

// ---------------- rec: recT[n][c] = relu(z @ m^T), hi/lo planes ----------------
__global__ __launch_bounds__(256) void k_rec(const ushort_t* __restrict__ zh,
    const ushort_t* __restrict__ zl,
    const ushort_t* __restrict__ mch, const ushort_t* __restrict__ mcl,
    ushort_t* __restrict__ recTh, ushort_t* __restrict__ recTl){
  __shared__ __align__(16) ushort_t sm[4*128*64];
  ushort_t* lAh = sm;
  ushort_t* lAl = sm + 128*64;
  ushort_t* lBh = sm + 2*128*64;
  ushort_t* lBl = sm + 3*128*64;
  int n0 = blockIdx.x*128, c0 = blockIdx.y*128, b = blockIdx.z;
  int tid = threadIdx.x, wid = tid>>6, lane = tid&63, quad = lane>>4, l16 = lane&15;
  int wm = wid>>1, wn = wid&1;
  f32x4 zero4 = {0.f,0.f,0.f,0.f};
  f32x4 acc[4][4];
  #pragma unroll
  for (int i=0;i<4;++i){
    #pragma unroll
    for (int j=0;j<4;++j) acc[i][j] = zero4;
  }
  stage_lds<128>(zh + ((size_t)b*NN + n0)*KC, KC, lAh, tid);
  stage_lds<128>(zl + ((size_t)b*NN + n0)*KC, KC, lAl, tid);
  stage_lds<128>(mch + ((size_t)b*CC + c0)*KC, KC, lBh, tid);
  stage_lds<128>(mcl + ((size_t)b*CC + c0)*KC, KC, lBl, tid);
  __syncthreads();
  #pragma unroll
  for (int kk = 0; kk < 64; kk += 32){
    bf16x8 ah[4], al[4], bh[4], bl[4];
    #pragma unroll
    for (int f=0; f<4; ++f){
      ah[f] = frag_ld(lAh, wm*64 + f*16 + l16, kk + quad*8);
      al[f] = frag_ld(lAl, wm*64 + f*16 + l16, kk + quad*8);
      bh[f] = frag_ld(lBh, wn*64 + f*16 + l16, kk + quad*8);
      bl[f] = frag_ld(lBl, wn*64 + f*16 + l16, kk + quad*8);
    }
    #pragma unroll
    for (int i=0;i<4;++i){
      #pragma unroll
      for (int j=0;j<4;++j){
        acc[i][j] = MFMA16(ah[i], bh[j], acc[i][j]);
        acc[i][j] = MFMA16(ah[i], bl[j], acc[i][j]);
        acc[i][j] = MFMA16(al[i], bh[j], acc[i][j]);
      }
    }
  }
  __syncthreads();
  ushort_t* ct = sm;
  // hi pass
  #pragma unroll
  for (int i=0;i<4;++i){
    #pragma unroll
    for (int r=0;r<4;++r){
      int m = wm*64 + i*16 + quad*4 + r;
      #pragma unroll
      for (int j=0;j<4;++j)
        ct[m*132 + (wn*64 + j*16 + l16)] = f2bu(fmaxf(acc[i][j][r], 0.f));
    }
  }
  __syncthreads();
  {
    ushort_t* rp = recTh + ((size_t)b*NN + n0)*CC + c0;
    #pragma unroll
    for (int i = 0; i < 16; ++i){
      int idx = tid + i*256;
      int m = idx >> 5, j4 = (idx & 31)*4;
      *(ushort4*)(rp + (size_t)m*CC + j4) = *(ushort4*)(ct + m*132 + j4);
    }
  }
  __syncthreads();
  // lo pass
  #pragma unroll
  for (int i=0;i<4;++i){
    #pragma unroll
    for (int r=0;r<4;++r){
      int m = wm*64 + i*16 + quad*4 + r;
      #pragma unroll
      for (int j=0;j<4;++j){
        float v = fmaxf(acc[i][j][r], 0.f);
        ct[m*132 + (wn*64 + j*16 + l16)] = lo_part(v, f2bu(v));
      }
    }
  }
  __syncthreads();
  {
    ushort_t* rp = recTl + ((size_t)b*NN + n0)*CC + c0;
    #pragma unroll
    for (int i = 0; i < 16; ++i){
      int idx = tid + i*256;
      int m = idx >> 5, j4 = (idx & 31)*4;
      *(ushort4*)(rp + (size_t)m*CC + j4) = *(ushort4*)(ct + m*132 + j4);
    }
  }
}

// ---------------- conv2 + BN -> out f32 [b][c][n] ----------------
__global__ __launch_bounds__(256) void k_conv2(const ushort_t* __restrict__ W2h,
    const ushort_t* __restrict__ W2l,
    const ushort_t* __restrict__ recTh, const ushort_t* __restrict__ recTl,
    const float* __restrict__ bnscale, const float* __restrict__ bnshift,
    float* __restrict__ out){
  __shared__ __align__(16) ushort_t sm[4*128*64];
  ushort_t* lAh = sm;
  ushort_t* lAl = sm + 128*64;
  ushort_t* lBh = sm + 2*128*64;
  ushort_t* lBl = sm + 3*128*64;
  int b = blockIdx.z, m0 = blockIdx.y*128, n0 = blockIdx.x*128;
  int tid = threadIdx.x, wid = tid>>6, lane = tid&63, quad = lane>>4, l16 = lane&15;
  int wm = wid>>1, wn = wid&1;
  f32x4 zero4 = {0.f,0.f,0.f,0.f};
  f32x4 acc[4][4];
  #pragma unroll
  for (int i=0;i<4;++i){
    #pragma unroll
    for (int j=0;j<4;++j) acc[i][j] = zero4;
  }
  const ushort_t* Aph = W2h + (size_t)m0*CC;
  const ushort_t* Apl = W2l + (size_t)m0*CC;
  const ushort_t* Bph = recTh + ((size_t)b*NN + n0)*CC;
  const ushort_t* Bpl = recTl + ((size_t)b*NN + n0)*CC;
  for (int k0 = 0; k0 < CC; k0 += 64){
    stage_lds<128>(Aph + k0, CC, lAh, tid);
    stage_lds<128>(Apl + k0, CC, lAl, tid);
    stage_lds<128>(Bph + k0, CC, lBh, tid);
    stage_lds<128>(Bpl + k0, CC, lBl, tid);
    __syncthreads();
    #pragma unroll
    for (int kk = 0; kk < 64; kk += 32){
      bf16x8 ah[4], al[4], bh[4], bl[4];
      #pragma unroll
      for (int f=0; f<4; ++f){
        ah[f] = frag_ld(lAh, wm*64 + f*16 + l16, kk + quad*8);
        al[f] = frag_ld(lAl, wm*64 + f*16 + l16, kk + quad*8);
        bh[f] = frag_ld(lBh, wn*64 + f*16 + l16, kk + quad*8);
        bl[f] = frag_ld(lBl, wn*64 + f*16 + l16, kk + quad*8);
      }
      #pragma unroll
      for (int i=0;i<4;++i){
        #pragma unroll
        for (int j=0;j<4;++j){
          acc[i][j] = MFMA16(ah[i], bh[j], acc[i][j]);
          acc[i][j] = MFMA16(ah[i], bl[j], acc[i][j]);
          acc[i][j] = MFMA16(al[i], bh[j], acc[i][j]);
        }
      }
    }
    __syncthreads();
  }
  size_t base = (size_t)b*CC*NN;
  #pragma unroll
  for (int i=0;i<4;++i){
    #pragma unroll
    for (int r=0;r<4;++r){
      int m = m0 + wm*64 + i*16 + quad*4 + r;
      float sc = bnscale[m], sh = bnshift[m];
      #pragma unroll
      for (int j=0;j<4;++j){
        int nn = n0 + wn*64 + j*16 + l16;
        out[base + (size_t)m*NN + nn] = acc[i][j][r]*sc + sh;
      }
    }
  }
}

extern "C" void kernel_launch(void* const* d_in, const int* in_sizes, int n_in,
                              void* d_out, int out_size, void* d_ws, size_t ws_size,
                              hipStream_t stream) {
  (void)in_sizes; (void)n_in; (void)out_size;
  const float* x     = (const float*)d_in[0];
  const float* W1    = (const float*)d_in[1];
  const float* b1    = (const float*)d_in[2];
  const float* mu    = (const float*)d_in[3];
  const float* W2    = (const float*)d_in[4];
  const float* gamma = (const float*)d_in[5];
  const float* beta  = (const float*)d_in[6];
  const float* mean  = (const float*)d_in[7];
  const float* var   = (const float*)d_in[8];
  float* out = (float*)d_out;

  const size_t big = (size_t)BB*NN*CC*2;      // 64 MiB
  const size_t zsz = (size_t)BB*NN*KC*2;      // 8 MiB
  const size_t msz = (size_t)BB*KC*CC*2;      // 4 MiB
  char* w = (char*)d_ws;
  ushort_t* xTh  = (ushort_t*)w;  w += big;   // live until last k_logits
  ushort_t* xfh  = (ushort_t*)w;  w += big;   // live until last k_mgemm
  ushort_t* zh   = (ushort_t*)w;  w += zsz;
  ushort_t* zl   = (ushort_t*)w;  w += zsz;
  ushort_t* zTh  = (ushort_t*)w;  w += zsz;
  ushort_t* zTl  = (ushort_t*)w;  w += zsz;
  float*    m_part = (float*)w;   w += (size_t)8*BB*KC*CC*4;   // 16 MiB
  ushort_t* mTh  = (ushort_t*)w;  w += msz;
  ushort_t* mTl  = (ushort_t*)w;  w += msz;
  ushort_t* mch  = (ushort_t*)w;  w += msz;
  ushort_t* mcl  = (ushort_t*)w;  w += msz;
  ushort_t* PTh  = (ushort_t*)w;  w += msz;
  ushort_t* PTl  = (ushort_t*)w;  w += msz;
  ushort_t* W1h  = (ushort_t*)w;  w += (size_t)CC*CC*2;
  ushort_t* W1l  = (ushort_t*)w;  w += (size_t)CC*CC*2;
  ushort_t* W1Th = (ushort_t*)w;  w += (size_t)CC*CC*2;
  ushort_t* W1Tl = (ushort_t*)w;  w += (size_t)CC*CC*2;
  ushort_t* W2h  = (ushort_t*)w;  w += (size_t)CC*CC*2;
  ushort_t* W2l  = (ushort_t*)w;  w += (size_t)CC*CC*2;
  float*    bnscale = (float*)w;  w += 2048;
  float*    bnshift = (float*)w;  w += 2048;
  float*    b1f  = (float*)w;     w += 2048;
  float*    colsum = (float*)w;   w += (size_t)BB*KC*4;
  float*    qbuf = (float*)w;     w += (size_t)BB*KC*4;
  // optional lo planes
  ushort_t* xTl = nullptr; ushort_t* xfl = nullptr;
  size_t used = (size_t)(w - (char*)d_ws);
  if (used + big <= ws_size){ xTl = (ushort_t*)w; w += big; used += big; }
  if (used + big <= ws_size){ xfl = (ushort_t*)w; w += big; used += big; }
  int hasxTl = xTl != nullptr, hasxfl = xfl != nullptr;
  // rec outputs reuse buffers dead by then: xfh (after last mgemm), xTh (after last logits)
  ushort_t* recTh = xfh;
  ushort_t* recTl = xTh;

  k_transpose<<<dim3(NN/64, CC/64, BB), 256, 0, stream>>>(x, xTh, xTl, hasxTl);
  k_prep<<<dim3((BB*KC*CC + 255)/256), 256, 0, stream>>>(gamma, beta, mean, var, b1,
      W1, W2, mu, bnscale, bnshift, b1f, W1h, W1l, W1Th, W1Tl, W2h, W2l, mTh, mTl);
  k_conv1r<<<dim3(NN/128, CC/128, BB), 256, 0, stream>>>(W1h, W1l, b1f, xTh, xTl, hasxTl,
      xfh, xfl, hasxfl);
  k_q<<<dim3(BB), 256, 0, stream>>>(b1f, mTh, mTl, qbuf);   // q for iteration 0 (m = mu)
  for (int it = 0; it < 3; ++it){
    (void)hipMemsetAsync(colsum, 0, (size_t)BB*KC*4, stream);
    k_wm2<<<dim3(CC/64, BB*KC/64), 256, 0, stream>>>(W1Th, W1Tl, mTh, mTl, PTh, PTl);
    k_logits<<<dim3(NN/128, BB), 256, 0, stream>>>(xTh, xTl, hasxTl, PTh, PTl, qbuf,
        zh, zl, (it == 2) ? 1 : 0, zTh, zTl, colsum);
    k_mgemm<<<dim3(CC/128, 8, BB), 256, 0, stream>>>(xfh, xfl, hasxfl, zTh, zTl, m_part);
    k_mnorm<<<dim3(KC, BB), 256, 0, stream>>>(m_part, colsum, b1f, mch, mcl, mTh, mTl, qbuf);
  }
  k_rec<<<dim3(NN/128, CC/128, BB), 256, 0, stream>>>(zh, zl, mch, mcl, recTh, recTl);
  k_conv2<<<dim3(NN/128, CC/128, BB), 256, 0, stream>>>(W2h, W2l, recTh, recTl,
      bnscale, bnshift, out);
}

// Round 7
// 752.912 us; speedup vs baseline: 1.1000x; 1.0708x over previous
//
#include <hip/hip_runtime.h>
#include <stdint.h>

#define BB 16
#define CC 512
#define NN 4096
#define KC 64

typedef unsigned short ushort_t;
typedef __attribute__((ext_vector_type(8))) __bf16 bf16x8;
typedef __attribute__((ext_vector_type(4))) float f32x4;

static __device__ __forceinline__ float bu2f(ushort_t u){
  union{unsigned int i; float f;} v; v.i = ((unsigned int)u)<<16; return v.f;
}
static __device__ __forceinline__ ushort_t f2bu(float f){
  unsigned int x = __float_as_uint(f);
  return (ushort_t)((x + 0x7FFFu + ((x>>16)&1u)) >> 16);
}
static __device__ __forceinline__ ushort_t lo_part(float v, ushort_t hi){
  return f2bu(v - bu2f(hi));
}

#define MFMA16(a,b,c) __builtin_amdgcn_mfma_f32_16x16x32_bf16(a,b,c,0,0,0)

// ---- staging: ROWS x 64 bf16 tile, global (row-major, ld elems) -> LDS ----
// LDS layout: linear 128B rows (pitch 64 elems), 16B segments XOR-swizzled:
//   LDS[row][s] holds global[row][s ^ (row&7)]  (s = 16B segment index 0..7)
// Loaded via global_load_lds(16B): dest is wave-uniform base + lane*16B, so
// the swizzle is applied on the per-lane GLOBAL source address (m173/m201).
template<int ROWS>
static __device__ __forceinline__ void stage_lds(const ushort_t* __restrict__ g, int ld,
                                                 ushort_t* l, int tid){
  int wid = tid >> 6, lane = tid & 63;
  #pragma unroll
  for (int it = 0; it < ROWS/32; ++it){
    int chunk = it*4 + wid;              // 1024B (8 rows) per wave-instruction
    int row = chunk*8 + (lane >> 3);
    int seg = (lane & 7) ^ (row & 7);    // pre-swizzled source segment
    const ushort_t* gp = g + (size_t)row*ld + seg*8;
    ushort_t* lp = l + chunk*512;        // wave-uniform; HW adds lane*16B
    __builtin_amdgcn_global_load_lds(
        (const __attribute__((address_space(1))) void*)gp,
        (__attribute__((address_space(3))) void*)lp, 16, 0, 0);
  }
}
// fragment read applies the same XOR involution (ko is a multiple of 8)
static __device__ __forceinline__ bf16x8 frag_ld(const ushort_t* l, int row, int ko){
  return *(const bf16x8*)(l + row*64 + (ko ^ ((row & 7) << 3)));
}

// ---- transpose x -> xT planes [b][n][c]; also emit xc planes [b][c][n] (elementwise) ----
__global__ __launch_bounds__(256) void k_transpose(const float* __restrict__ x,
    ushort_t* __restrict__ xTh, ushort_t* __restrict__ xTl, int hasLo,
    ushort_t* __restrict__ xch, ushort_t* __restrict__ xcl, int hasClo){
  __shared__ ushort_t th[64][68];
  __shared__ ushort_t tl[64][68];
  int b = blockIdx.z, c0 = blockIdx.y*64, n0 = blockIdx.x*64;
  int r16 = threadIdx.x >> 4;
  int q4  = (threadIdx.x & 15) * 4;
  int needLo = hasLo | hasClo;
  #pragma unroll
  for (int p = 0; p < 4; ++p){
    int row = r16 + p*16;   // c index within tile
    size_t off = ((size_t)b*CC + c0 + row)*NN + n0 + q4;
    float4 v = *(const float4*)(x + off);
    ushort_t h0=f2bu(v.x), h1=f2bu(v.y), h2=f2bu(v.z), h3=f2bu(v.w);
    th[q4+0][row]=h0; th[q4+1][row]=h1; th[q4+2][row]=h2; th[q4+3][row]=h3;
    ushort_t l0=0,l1=0,l2=0,l3=0;
    if (needLo){
      l0=lo_part(v.x,h0); l1=lo_part(v.y,h1);
      l2=lo_part(v.z,h2); l3=lo_part(v.w,h3);
      tl[q4+0][row]=l0; tl[q4+1][row]=l1; tl[q4+2][row]=l2; tl[q4+3][row]=l3;
    }
    // xc planes: same layout as input x, elementwise bf16 split (coalesced)
    ushort4 vh; vh.x=h0; vh.y=h1; vh.z=h2; vh.w=h3;
    *(ushort4*)(xch + off) = vh;
    if (hasClo){
      ushort4 ul; ul.x=l0; ul.y=l1; ul.z=l2; ul.w=l3;
      *(ushort4*)(xcl + off) = ul;
    }
  }
  __syncthreads();
  #pragma unroll
  for (int p = 0; p < 4; ++p){
    int nrow = r16 + p*16;
    size_t off = ((size_t)b*NN + n0 + nrow)*CC + c0 + q4;
    ushort4 v;
    v.x = th[nrow][q4+0]; v.y = th[nrow][q4+1]; v.z = th[nrow][q4+2]; v.w = th[nrow][q4+3];
    *(ushort4*)(xTh + off) = v;
    if (hasLo){
      ushort4 u;
      u.x = tl[nrow][q4+0]; u.y = tl[nrow][q4+1]; u.z = tl[nrow][q4+2]; u.w = tl[nrow][q4+3];
      *(ushort4*)(xTl + off) = u;
    }
  }
}

// ---- prep: W1 (row-major + transposed) hi-lo, W2 hi-lo, mu->mT hi-lo, BN, bias ----
__global__ __launch_bounds__(256) void k_prep(const float* __restrict__ gamma,
    const float* __restrict__ beta, const float* __restrict__ mean,
    const float* __restrict__ var, const float* __restrict__ b1,
    const float* __restrict__ W1, const float* __restrict__ W2,
    const float* __restrict__ mu,
    float* __restrict__ bnscale, float* __restrict__ bnshift,
    float* __restrict__ b1f,
    ushort_t* __restrict__ W1h, ushort_t* __restrict__ W1l,
    ushort_t* __restrict__ W1Th, ushort_t* __restrict__ W1Tl,
    ushort_t* __restrict__ W2h, ushort_t* __restrict__ W2l,
    ushort_t* __restrict__ mTh, ushort_t* __restrict__ mTl){
  int t = blockIdx.x*256 + threadIdx.x;
  if (t < CC){
    float inv = gamma[t] * rsqrtf(var[t] + 1e-5f);
    bnscale[t] = inv;
    bnshift[t] = beta[t] - mean[t]*inv;
    b1f[t] = b1[t];
  }
  if (t < CC*CC){
    int o = t >> 9, c = t & (CC-1);
    float w1 = W1[t], w2 = W2[t];
    ushort_t h1 = f2bu(w1), h2 = f2bu(w2);
    W1h[t] = h1; W1l[t] = lo_part(w1,h1);
    W1Th[(size_t)c*CC + o] = h1; W1Tl[(size_t)c*CC + o] = lo_part(w1,h1);
    W2h[t] = h2; W2l[t] = lo_part(w2,h2);
  }
  if (t < BB*KC*CC){
    int c = t & (CC-1);
    int k = (t >> 9) & (KC-1);
    float v = mu[(size_t)c*KC + k];
    ushort_t h = f2bu(v);
    mTh[t] = h; mTl[t] = lo_part(v,h);
  }
}

// ---- q[b][k] = sum_o b1[o]*m[o,k]  (iteration 0); also zeroes colsum ----
__global__ __launch_bounds__(256) void k_q(const float* __restrict__ b1f,
    const ushort_t* __restrict__ mTh, const ushort_t* __restrict__ mTl,
    float* __restrict__ qout, float* __restrict__ colsum){
  int b = blockIdx.x, t = threadIdx.x;
  if (t < KC) colsum[b*KC + t] = 0.f;
  int k = t & 63, seg = t >> 6;
  const ushort_t* mh = mTh + (size_t)b*KC*CC + (size_t)k*CC;
  const ushort_t* ml = mTl + (size_t)b*KC*CC + (size_t)k*CC;
  float s = 0.f;
  #pragma unroll 4
  for (int o = seg*128; o < seg*128 + 128; ++o)
    s += b1f[o]*(bu2f(mh[o]) + bu2f(ml[o]));
  __shared__ float red[256];
  red[t] = s; __syncthreads();
  if (seg == 0) qout[b*KC + k] = red[k] + red[64+k] + red[128+k] + red[192+k];
}

// ---- P^T: batched GEMM over flat [1024][512] m matrix: PT[bk][c] = (W1^T m)[c,bk] ----
__global__ __launch_bounds__(256) void k_wm2(const ushort_t* __restrict__ W1Th,
    const ushort_t* __restrict__ W1Tl,
    const ushort_t* __restrict__ mTh, const ushort_t* __restrict__ mTl,
    ushort_t* __restrict__ PTh, ushort_t* __restrict__ PTl){
  __shared__ __align__(16) ushort_t sm[4*64*64];   // 32 KiB
  ushort_t* lAh = sm;
  ushort_t* lAl = sm + 4096;
  ushort_t* lBh = sm + 8192;
  ushort_t* lBl = sm + 12288;
  int c0 = blockIdx.x*64, bk0 = blockIdx.y*64;
  int tid = threadIdx.x, wid = tid>>6, lane = tid&63, quad = lane>>4, l16 = lane&15;
  f32x4 zero4 = {0.f,0.f,0.f,0.f};
  f32x4 acc[4];
  #pragma unroll
  for (int j=0;j<4;++j) acc[j] = zero4;
  const ushort_t* Aph = W1Th + (size_t)c0*CC;
  const ushort_t* Apl = W1Tl + (size_t)c0*CC;
  const ushort_t* Bph = mTh + (size_t)bk0*CC;   // m flat [1024][512]
  const ushort_t* Bpl = mTl + (size_t)bk0*CC;
  for (int k0 = 0; k0 < CC; k0 += 64){
    stage_lds<64>(Aph + k0, CC, lAh, tid);
    stage_lds<64>(Apl + k0, CC, lAl, tid);
    stage_lds<64>(Bph + k0, CC, lBh, tid);
    stage_lds<64>(Bpl + k0, CC, lBl, tid);
    __syncthreads();
    #pragma unroll
    for (int kk = 0; kk < 64; kk += 32){
      bf16x8 ah, al, bh[4], bl[4];
      ah = frag_ld(lAh, wid*16 + l16, kk + quad*8);
      al = frag_ld(lAl, wid*16 + l16, kk + quad*8);
      #pragma unroll
      for (int f=0; f<4; ++f){
        bh[f] = frag_ld(lBh, f*16 + l16, kk + quad*8);
        bl[f] = frag_ld(lBl, f*16 + l16, kk + quad*8);
      }
      #pragma unroll
      for (int j=0;j<4;++j){
        acc[j] = MFMA16(ah, bh[j], acc[j]);
        acc[j] = MFMA16(ah, bl[j], acc[j]);
        acc[j] = MFMA16(al, bh[j], acc[j]);
      }
    }
    __syncthreads();
  }
  int cbase = c0 + wid*16 + quad*4;
  #pragma unroll
  for (int j=0;j<4;++j){
    int bk = bk0 + j*16 + l16;
    ushort4 vh, vl;
    float a0=acc[j][0], a1=acc[j][1], a2=acc[j][2], a3=acc[j][3];
    vh.x=f2bu(a0); vh.y=f2bu(a1); vh.z=f2bu(a2); vh.w=f2bu(a3);
    vl.x=lo_part(a0,vh.x); vl.y=lo_part(a1,vh.y); vl.z=lo_part(a2,vh.z); vl.w=lo_part(a3,vh.w);
    size_t off = (size_t)bk*CC + cbase;
    *(ushort4*)(PTh + off) = vh;
    *(ushort4*)(PTl + off) = vl;
  }
}

// ---- logits(from xT,P) + softmax + colsum -> z, zT ----
__global__ __launch_bounds__(256) void k_logits(const ushort_t* __restrict__ xTh,
    const ushort_t* __restrict__ xTl, int hasAl,
    const ushort_t* __restrict__ PTh, const ushort_t* __restrict__ PTl,
    const float* __restrict__ q,
    ushort_t* __restrict__ zh, ushort_t* __restrict__ zl, int writeZ,
    ushort_t* __restrict__ zTh, ushort_t* __restrict__ zTl,
    float* __restrict__ colsum){
  __shared__ __align__(16) ushort_t sm[2*128*64 + 2*64*64];
  ushort_t* lAh = sm;
  ushort_t* lAl = sm + 128*64;
  ushort_t* lBh = sm + 2*128*64;
  ushort_t* lBl = sm + 2*128*64 + 64*64;
  int b = blockIdx.y, n0 = blockIdx.x*128;
  int tid = threadIdx.x, wid = tid>>6, lane = tid&63, quad = lane>>4, l16 = lane&15;
  f32x4 zero4 = {0.f,0.f,0.f,0.f};
  f32x4 acc[2][4];
  #pragma unroll
  for (int i=0;i<2;++i){
    #pragma unroll
    for (int j=0;j<4;++j) acc[i][j] = zero4;
  }
  const ushort_t* Aph = xTh + ((size_t)b*NN + n0)*CC;
  const ushort_t* Apl = hasAl ? xTl + ((size_t)b*NN + n0)*CC : nullptr;
  const ushort_t* Bph = PTh + (size_t)b*KC*CC;
  const ushort_t* Bpl = PTl + (size_t)b*KC*CC;
  for (int k0 = 0; k0 < CC; k0 += 64){
    stage_lds<128>(Aph + k0, CC, lAh, tid);
    if (hasAl) stage_lds<128>(Apl + k0, CC, lAl, tid);
    stage_lds<64>(Bph + k0, CC, lBh, tid);
    stage_lds<64>(Bpl + k0, CC, lBl, tid);
    __syncthreads();
    #pragma unroll
    for (int kk = 0; kk < 64; kk += 32){
      bf16x8 ah[2], al[2], bh[4], bl[4];
      #pragma unroll
      for (int f=0; f<2; ++f){
        ah[f] = frag_ld(lAh, wid*32 + f*16 + l16, kk + quad*8);
        if (hasAl) al[f] = frag_ld(lAl, wid*32 + f*16 + l16, kk + quad*8);
      }
      #pragma unroll
      for (int f=0; f<4; ++f){
        bh[f] = frag_ld(lBh, f*16 + l16, kk + quad*8);
        bl[f] = frag_ld(lBl, f*16 + l16, kk + quad*8);
      }
      #pragma unroll
      for (int i=0;i<2;++i){
        #pragma unroll
        for (int j=0;j<4;++j){
          acc[i][j] = MFMA16(ah[i], bh[j], acc[i][j]);
          acc[i][j] = MFMA16(ah[i], bl[j], acc[i][j]);
        }
      }
      if (hasAl){
        #pragma unroll
        for (int i=0;i<2;++i){
          #pragma unroll
          for (int j=0;j<4;++j) acc[i][j] = MFMA16(al[i], bh[j], acc[i][j]);
        }
      }
    }
    __syncthreads();
  }
  // + bias-term q[k], then softmax over 64 cols per row
  float qv[4];
  #pragma unroll
  for (int j=0;j<4;++j) qv[j] = q[b*KC + j*16 + l16];
  #pragma unroll
  for (int i=0;i<2;++i){
    #pragma unroll
    for (int r=0;r<4;++r){
      #pragma unroll
      for (int j=0;j<4;++j) acc[i][j][r] += qv[j];
      float mx = fmaxf(fmaxf(acc[i][0][r], acc[i][1][r]), fmaxf(acc[i][2][r], acc[i][3][r]));
      mx = fmaxf(mx, __shfl_xor(mx, 1));
      mx = fmaxf(mx, __shfl_xor(mx, 2));
      mx = fmaxf(mx, __shfl_xor(mx, 4));
      mx = fmaxf(mx, __shfl_xor(mx, 8));
      float e0 = __expf(acc[i][0][r]-mx), e1 = __expf(acc[i][1][r]-mx);
      float e2 = __expf(acc[i][2][r]-mx), e3 = __expf(acc[i][3][r]-mx);
      float s = e0+e1+e2+e3;
      s += __shfl_xor(s, 1); s += __shfl_xor(s, 2);
      s += __shfl_xor(s, 4); s += __shfl_xor(s, 8);
      float inv = 1.0f/s;
      acc[i][0][r] = e0*inv; acc[i][1][r] = e1*inv;
      acc[i][2][r] = e2*inv; acc[i][3][r] = e3*inv;
    }
  }
  // column sums -> atomics
  #pragma unroll
  for (int j=0;j<4;++j){
    float p = 0.f;
    #pragma unroll
    for (int i=0;i<2;++i){
      #pragma unroll
      for (int r=0;r<4;++r) p += acc[i][j][r];
    }
    p += __shfl_xor(p, 16); p += __shfl_xor(p, 32);
    if (lane < 16) atomicAdd(&colsum[b*KC + j*16 + l16], p);
  }
  // stores: zT always; z[n][k] planes only last iteration (for k_rec)
  #pragma unroll
  for (int i=0;i<2;++i){
    int nbase = wid*32 + i*16 + quad*4;
    #pragma unroll
    for (int j=0;j<4;++j){
      int k = j*16 + l16;
      ushort4 vh, vl;
      float a0=acc[i][j][0], a1=acc[i][j][1], a2=acc[i][j][2], a3=acc[i][j][3];
      vh.x=f2bu(a0); vh.y=f2bu(a1); vh.z=f2bu(a2); vh.w=f2bu(a3);
      vl.x=lo_part(a0,vh.x); vl.y=lo_part(a1,vh.y); vl.z=lo_part(a2,vh.z); vl.w=lo_part(a3,vh.w);
      size_t zoff = ((size_t)b*KC + k)*NN + n0 + nbase;
      *(ushort4*)(zTh + zoff) = vh;
      *(ushort4*)(zTl + zoff) = vl;
      if (writeZ){
        const ushort_t* ph = (const ushort_t*)&vh;
        const ushort_t* pl = (const ushort_t*)&vl;
        #pragma unroll
        for (int r=0;r<4;++r){
          size_t o = ((size_t)b*NN + n0 + nbase + r)*KC + k;
          zh[o] = ph[r]; zl[o] = pl[r];
        }
      }
    }
  }
}

// ---- y-GEMM split-K: y_part[s][b][k][c] = x @ z_slice (A = x bf16 planes) ----
__global__ __launch_bounds__(256) void k_mgemm(const ushort_t* __restrict__ xch,
    const ushort_t* __restrict__ xcl, int hasAl,
    const ushort_t* __restrict__ zTh, const ushort_t* __restrict__ zTl,
    float* __restrict__ y_part){
  __shared__ __align__(16) ushort_t sm[2*128*64 + 2*64*64];
  ushort_t* lAh = sm;
  ushort_t* lAl = sm + 128*64;
  ushort_t* lBh = sm + 2*128*64;
  ushort_t* lBl = sm + 2*128*64 + 64*64;
  int c0 = blockIdx.x*128, slice = blockIdx.y, b = blockIdx.z;
  int tid = threadIdx.x, wid = tid>>6, lane = tid&63, quad = lane>>4, l16 = lane&15;
  f32x4 zero4 = {0.f,0.f,0.f,0.f};
  f32x4 acc[2][4];
  #pragma unroll
  for (int i=0;i<2;++i){
    #pragma unroll
    for (int j=0;j<4;++j) acc[i][j] = zero4;
  }
  const ushort_t* Aph = xch + ((size_t)b*CC + c0)*NN + slice*512;
  const ushort_t* Apl = hasAl ? xcl + ((size_t)b*CC + c0)*NN + slice*512 : nullptr;
  const ushort_t* Bph = zTh + (size_t)b*KC*NN + slice*512;
  const ushort_t* Bpl = zTl + (size_t)b*KC*NN + slice*512;
  for (int k0 = 0; k0 < 512; k0 += 64){
    stage_lds<128>(Aph + k0, NN, lAh, tid);
    if (hasAl) stage_lds<128>(Apl + k0, NN, lAl, tid);
    stage_lds<64>(Bph + k0, NN, lBh, tid);
    stage_lds<64>(Bpl + k0, NN, lBl, tid);
    __syncthreads();
    #pragma unroll
    for (int kk = 0; kk < 64; kk += 32){
      bf16x8 ah[2], al[2], bh[4], bl[4];
      #pragma unroll
      for (int f=0; f<2; ++f){
        ah[f] = frag_ld(lAh, wid*32 + f*16 + l16, kk + quad*8);
        if (hasAl) al[f] = frag_ld(lAl, wid*32 + f*16 + l16, kk + quad*8);
      }
      #pragma unroll
      for (int f=0; f<4; ++f){
        bh[f] = frag_ld(lBh, f*16 + l16, kk + quad*8);
        bl[f] = frag_ld(lBl, f*16 + l16, kk + quad*8);
      }
      #pragma unroll
      for (int i=0;i<2;++i){
        #pragma unroll
        for (int j=0;j<4;++j){
          acc[i][j] = MFMA16(ah[i], bh[j], acc[i][j]);
          acc[i][j] = MFMA16(ah[i], bl[j], acc[i][j]);
        }
      }
      if (hasAl){
        #pragma unroll
        for (int i=0;i<2;++i){
          #pragma unroll
          for (int j=0;j<4;++j) acc[i][j] = MFMA16(al[i], bh[j], acc[i][j]);
        }
      }
    }
    __syncthreads();
  }
  #pragma unroll
  for (int i=0;i<2;++i){
    int c = c0 + wid*32 + i*16 + quad*4;
    #pragma unroll
    for (int j=0;j<4;++j){
      int k = j*16 + l16;
      *(f32x4*)(y_part + (((size_t)slice*BB + b)*KC + k)*CC + c) = acc[i][j];
    }
  }
}

// ---- reduce y_part slices, scale by 1/(eps+colsum) -> y bf16 planes [bk][c] ----
__global__ __launch_bounds__(256) void k_ymerge(const float* __restrict__ y_part,
    const float* __restrict__ colsum,
    ushort_t* __restrict__ yh, ushort_t* __restrict__ yl){
  int k = blockIdx.x, b = blockIdx.y, t = threadIdx.x;
  float v0 = 0.f, v1 = 0.f;
  #pragma unroll
  for (int s = 0; s < 8; ++s){
    const float* p = y_part + (((size_t)s*BB + b)*KC + k)*CC;
    v0 += p[t]; v1 += p[t+256];
  }
  float sk = 1.0f/(1e-6f + colsum[b*KC + k]);
  v0 *= sk; v1 *= sk;
  ushort_t h0 = f2bu(v0), h1 = f2bu(v1);
  size_t o = (size_t)(b*KC + k)*CC + t;
  yh[o] = h0; yh[o+256] = h1;
  yl[o] = lo_part(v0,h0); yl[o+256] = lo_part(v1,h1);
}

// ---- W1-lift: m_pre[bk][o] f32 = (W1 @ y)[o][bk]  (clone of k_wm2, f32 epilogue) ----
__global__ __launch_bounds__(256) void k_wm3(const ushort_t* __restrict__ W1h,
    const ushort_t* __restrict__ W1l,
    const ushort_t* __restrict__ yh, const ushort_t* __restrict__ yl,
    float* __restrict__ m_pre){
  __shared__ __align__(16) ushort_t sm[4*64*64];   // 32 KiB
  ushort_t* lAh = sm;
  ushort_t* lAl = sm + 4096;
  ushort_t* lBh = sm + 8192;
  ushort_t* lBl = sm + 12288;
  int o0 = blockIdx.x*64, bk0 = blockIdx.y*64;
  int tid = threadIdx.x, wid = tid>>6, lane = tid&63, quad = lane>>4, l16 = lane&15;
  f32x4 zero4 = {0.f,0.f,0.f,0.f};
  f32x4 acc[4];
  #pragma unroll
  for (int j=0;j<4;++j) acc[j] = zero4;
  const ushort_t* Aph = W1h + (size_t)o0*CC;
  const ushort_t* Apl = W1l + (size_t)o0*CC;
  const ushort_t* Bph = yh + (size_t)bk0*CC;
  const ushort_t* Bpl = yl + (size_t)bk0*CC;
  for (int k0 = 0; k0 < CC; k0 += 64){
    stage_lds<64>(Aph + k0, CC, lAh, tid);
    stage_lds<64>(Apl + k0, CC, lAl, tid);
    stage_lds<64>(Bph + k0, CC, lBh, tid);
    stage_lds<64>(Bpl + k0, CC, lBl, tid);
    __syncthreads();
    #pragma unroll
    for (int kk = 0; kk < 64; kk += 32){
      bf16x8 ah, al, bh[4], bl[4];
      ah = frag_ld(lAh, wid*16 + l16, kk + quad*8);
      al = frag_ld(lAl, wid*16 + l16, kk + quad*8);
      #pragma unroll
      for (int f=0; f<4; ++f){
        bh[f] = frag_ld(lBh, f*16 + l16, kk + quad*8);
        bl[f] = frag_ld(lBl, f*16 + l16, kk + quad*8);
      }
      #pragma unroll
      for (int j=0;j<4;++j){
        acc[j] = MFMA16(ah, bh[j], acc[j]);
        acc[j] = MFMA16(ah, bl[j], acc[j]);
        acc[j] = MFMA16(al, bh[j], acc[j]);
      }
    }
    __syncthreads();
  }
  int obase = o0 + wid*16 + quad*4;
  #pragma unroll
  for (int j=0;j<4;++j){
    int bk = bk0 + j*16 + l16;
    *(f32x4*)(m_pre + (size_t)bk*CC + obase) = acc[j];
  }
}

// ---- finalize m: + b1*cs*sk, l2-normalize, split hi/lo both layouts, q; zero colsum ----
__global__ __launch_bounds__(256) void k_l2q(const float* __restrict__ m_pre,
    float* __restrict__ colsum, const float* __restrict__ b1f,
    ushort_t* __restrict__ mch, ushort_t* __restrict__ mcl,
    ushort_t* __restrict__ mTh, ushort_t* __restrict__ mTl,
    float* __restrict__ qout){
  int k = blockIdx.x, b = blockIdx.y, t = threadIdx.x;
  int bk = b*KC + k;
  float cs = colsum[bk];
  float bfac = cs/(1e-6f + cs);
  float v0 = m_pre[(size_t)bk*CC + t]       + b1f[t]*bfac;
  float v1 = m_pre[(size_t)bk*CC + t + 256] + b1f[t+256]*bfac;
  float ss = v0*v0 + v1*v1;
  #pragma unroll
  for (int off = 1; off < 64; off <<= 1) ss += __shfl_xor(ss, off);
  __shared__ float red[4];
  if ((t&63) == 0) red[t>>6] = ss;
  __syncthreads();
  float inv = 1.0f/(1e-6f + sqrtf(red[0]+red[1]+red[2]+red[3]));
  v0 *= inv; v1 *= inv;
  ushort_t h0 = f2bu(v0), h1 = f2bu(v1);
  ushort_t l0 = lo_part(v0,h0), l1 = lo_part(v1,h1);
  size_t to = (size_t)bk*CC + t;
  mTh[to] = h0; mTh[to+256] = h1;
  mTl[to] = l0; mTl[to+256] = l1;
  size_t co = ((size_t)b*CC + t)*KC + k;
  mch[co] = h0; mch[co + (size_t)256*KC] = h1;
  mcl[co] = l0; mcl[co + (size_t)256*KC] = l1;
  // q for next iteration: sum_o b1[o] * m_rounded[o][k]
  float qs = b1f[t]*(bu2f(h0)+bu2f(l0)) + b1f[t+256]*(bu2f(h1)+bu2f(l1));
  #pragma unroll
  for (int off = 1; off < 64; off <<= 1) qs += __shfl_xor(qs, off);
  __shared__ float red2[4];
  __syncthreads();
  if ((t&63) == 0) red2[t>>6] = qs;
  __syncthreads();
  if (t == 0){
    qout[bk] = red2[0]+red2[1]+red2[2]+red2[3];
    colsum[bk] = 0.f;   // ready for next iteration's logits atomics
  }
}

// ---- rec: recT[n][c] = relu(z @ m^T), hi/lo planes ----
__global__ __launch_bounds__(256) void k_rec(const ushort_t* __restrict__ zh,
    const ushort_t* __restrict__ zl,
    const ushort_t* __restrict__ mch, const ushort_t* __restrict__ mcl,
    ushort_t* __restrict__ recTh, ushort_t* __restrict__ recTl){
  __shared__ __align__(16) ushort_t sm[4*128*64];
  ushort_t* lAh = sm;
  ushort_t* lAl = sm + 128*64;
  ushort_t* lBh = sm + 2*128*64;
  ushort_t* lBl = sm + 3*128*64;
  int n0 = blockIdx.x*128, c0 = blockIdx.y*128, b = blockIdx.z;
  int tid = threadIdx.x, wid = tid>>6, lane = tid&63, quad = lane>>4, l16 = lane&15;
  int wm = wid>>1, wn = wid&1;
  f32x4 zero4 = {0.f,0.f,0.f,0.f};
  f32x4 acc[4][4];
  #pragma unroll
  for (int i=0;i<4;++i){
    #pragma unroll
    for (int j=0;j<4;++j) acc[i][j] = zero4;
  }
  stage_lds<128>(zh + ((size_t)b*NN + n0)*KC, KC, lAh, tid);
  stage_lds<128>(zl + ((size_t)b*NN + n0)*KC, KC, lAl, tid);
  stage_lds<128>(mch + ((size_t)b*CC + c0)*KC, KC, lBh, tid);
  stage_lds<128>(mcl + ((size_t)b*CC + c0)*KC, KC, lBl, tid);
  __syncthreads();
  #pragma unroll
  for (int kk = 0; kk < 64; kk += 32){
    bf16x8 ah[4], al[4], bh[4], bl[4];
    #pragma unroll
    for (int f=0; f<4; ++f){
      ah[f] = frag_ld(lAh, wm*64 + f*16 + l16, kk + quad*8);
      al[f] = frag_ld(lAl, wm*64 + f*16 + l16, kk + quad*8);
      bh[f] = frag_ld(lBh, wn*64 + f*16 + l16, kk + quad*8);
      bl[f] = frag_ld(lBl, wn*64 + f*16 + l16, kk + quad*8);
    }
    #pragma unroll
    for (int i=0;i<4;++i){
      #pragma unroll
      for (int j=0;j<4;++j){
        acc[i][j] = MFMA16(ah[i], bh[j], acc[i][j]);
        acc[i][j] = MFMA16(ah[i], bl[j], acc[i][j]);
        acc[i][j] = MFMA16(al[i], bh[j], acc[i][j]);
      }
    }
  }
  __syncthreads();
  ushort_t* ct = sm;
  // hi pass
  #pragma unroll
  for (int i=0;i<4;++i){
    #pragma unroll
    for (int r=0;r<4;++r){
      int m = wm*64 + i*16 + quad*4 + r;
      #pragma unroll
      for (int j=0;j<4;++j)
        ct[m*132 + (wn*64 + j*16 + l16)] = f2bu(fmaxf(acc[i][j][r], 0.f));
    }
  }
  __syncthreads();
  {
    ushort_t* rp = recTh + ((size_t)b*NN + n0)*CC + c0;
    #pragma unroll
    for (int i = 0; i < 16; ++i){
      int idx = tid + i*256;
      int m = idx >> 5, j4 = (idx & 31)*4;
      *(ushort4*)(rp + (size_t)m*CC + j4) = *(ushort4*)(ct + m*132 + j4);
    }
  }
  __syncthreads();
  // lo pass
  #pragma unroll
  for (int i=0;i<4;++i){
    #pragma unroll
    for (int r=0;r<4;++r){
      int m = wm*64 + i*16 + quad*4 + r;
      #pragma unroll
      for (int j=0;j<4;++j){
        float v = fmaxf(acc[i][j][r], 0.f);
        ct[m*132 + (wn*64 + j*16 + l16)] = lo_part(v, f2bu(v));
      }
    }
  }
  __syncthreads();
  {
    ushort_t* rp = recTl + ((size_t)b*NN + n0)*CC + c0;
    #pragma unroll
    for (int i = 0; i < 16; ++i){
      int idx = tid + i*256;
      int m = idx >> 5, j4 = (idx & 31)*4;
      *(ushort4*)(rp + (size_t)m*CC + j4) = *(ushort4*)(ct + m*132 + j4);
    }
  }
}

// ---- conv2 + BN -> out f32 [b][c][n] ----
__global__ __launch_bounds__(256) void k_conv2(const ushort_t* __restrict__ W2h,
    const ushort_t* __restrict__ W2l,
    const ushort_t* __restrict__ recTh, const ushort_t* __restrict__ recTl,
    const float* __restrict__ bnscale, const float* __restrict__ bnshift,
    float* __restrict__ out){
  __shared__ __align__(16) ushort_t sm[4*128*64];
  ushort_t* lAh = sm;
  ushort_t* lAl = sm + 128*64;
  ushort_t* lBh = sm + 2*128*64;
  ushort_t* lBl = sm + 3*128*64;
  int b = blockIdx.z, m0 = blockIdx.y*128, n0 = blockIdx.x*128;
  int tid = threadIdx.x, wid = tid>>6, lane = tid&63, quad = lane>>4, l16 = lane&15;
  int wm = wid>>1, wn = wid&1;
  f32x4 zero4 = {0.f,0.f,0.f,0.f};
  f32x4 acc[4][4];
  #pragma unroll
  for (int i=0;i<4;++i){
    #pragma unroll
    for (int j=0;j<4;++j) acc[i][j] = zero4;
  }
  const ushort_t* Aph = W2h + (size_t)m0*CC;
  const ushort_t* Apl = W2l + (size_t)m0*CC;
  const ushort_t* Bph = recTh + ((size_t)b*NN + n0)*CC;
  const ushort_t* Bpl = recTl + ((size_t)b*NN + n0)*CC;
  for (int k0 = 0; k0 < CC; k0 += 64){
    stage_lds<128>(Aph + k0, CC, lAh, tid);
    stage_lds<128>(Apl + k0, CC, lAl, tid);
    stage_lds<128>(Bph + k0, CC, lBh, tid);
    stage_lds<128>(Bpl + k0, CC, lBl, tid);
    __syncthreads();
    #pragma unroll
    for (int kk = 0; kk < 64; kk += 32){
      bf16x8 ah[4], al[4], bh[4], bl[4];
      #pragma unroll
      for (int f=0; f<4; ++f){
        ah[f] = frag_ld(lAh, wm*64 + f*16 + l16, kk + quad*8);
        al[f] = frag_ld(lAl, wm*64 + f*16 + l16, kk + quad*8);
        bh[f] = frag_ld(lBh, wn*64 + f*16 + l16, kk + quad*8);
        bl[f] = frag_ld(lBl, wn*64 + f*16 + l16, kk + quad*8);
      }
      #pragma unroll
      for (int i=0;i<4;++i){
        #pragma unroll
        for (int j=0;j<4;++j){
          acc[i][j] = MFMA16(ah[i], bh[j], acc[i][j]);
          acc[i][j] = MFMA16(ah[i], bl[j], acc[i][j]);
          acc[i][j] = MFMA16(al[i], bh[j], acc[i][j]);
        }
      }
    }
    __syncthreads();
  }
  size_t base = (size_t)b*CC*NN;
  #pragma unroll
  for (int i=0;i<4;++i){
    #pragma unroll
    for (int r=0;r<4;++r){
      int m = m0 + wm*64 + i*16 + quad*4 + r;
      float sc = bnscale[m], sh = bnshift[m];
      #pragma unroll
      for (int j=0;j<4;++j){
        int nn = n0 + wn*64 + j*16 + l16;
        out[base + (size_t)m*NN + nn] = acc[i][j][r]*sc + sh;
      }
    }
  }
}

extern "C" void kernel_launch(void* const* d_in, const int* in_sizes, int n_in,
                              void* d_out, int out_size, void* d_ws, size_t ws_size,
                              hipStream_t stream) {
  (void)in_sizes; (void)n_in; (void)out_size;
  const float* x     = (const float*)d_in[0];
  const float* W1    = (const float*)d_in[1];
  const float* b1    = (const float*)d_in[2];
  const float* mu    = (const float*)d_in[3];
  const float* W2    = (const float*)d_in[4];
  const float* gamma = (const float*)d_in[5];
  const float* beta  = (const float*)d_in[6];
  const float* mean  = (const float*)d_in[7];
  const float* var   = (const float*)d_in[8];
  float* out = (float*)d_out;

  const size_t big = (size_t)BB*NN*CC*2;      // 64 MiB
  const size_t zsz = (size_t)BB*NN*KC*2;      // 8 MiB
  const size_t msz = (size_t)BB*KC*CC*2;      // 1 MiB
  char* w = (char*)d_ws;
  ushort_t* xTh  = (ushort_t*)w;  w += big;   // live until last k_logits
  ushort_t* xch  = (ushort_t*)w;  w += big;   // live until last k_mgemm
  ushort_t* zh   = (ushort_t*)w;  w += zsz;
  ushort_t* zl   = (ushort_t*)w;  w += zsz;
  ushort_t* zTh  = (ushort_t*)w;  w += zsz;
  ushort_t* zTl  = (ushort_t*)w;  w += zsz;
  float*    y_part = (float*)w;   w += (size_t)8*BB*KC*CC*4;   // 16 MiB
  float*    m_pre  = (float*)w;   w += (size_t)BB*KC*CC*4;     // 2 MiB
  ushort_t* mTh  = (ushort_t*)w;  w += msz;
  ushort_t* mTl  = (ushort_t*)w;  w += msz;
  ushort_t* mch  = (ushort_t*)w;  w += msz;
  ushort_t* mcl  = (ushort_t*)w;  w += msz;
  ushort_t* PTh  = (ushort_t*)w;  w += msz;
  ushort_t* PTl  = (ushort_t*)w;  w += msz;
  ushort_t* yh   = (ushort_t*)w;  w += msz;
  ushort_t* yl   = (ushort_t*)w;  w += msz;
  ushort_t* W1h  = (ushort_t*)w;  w += (size_t)CC*CC*2;
  ushort_t* W1l  = (ushort_t*)w;  w += (size_t)CC*CC*2;
  ushort_t* W1Th = (ushort_t*)w;  w += (size_t)CC*CC*2;
  ushort_t* W1Tl = (ushort_t*)w;  w += (size_t)CC*CC*2;
  ushort_t* W2h  = (ushort_t*)w;  w += (size_t)CC*CC*2;
  ushort_t* W2l  = (ushort_t*)w;  w += (size_t)CC*CC*2;
  float*    bnscale = (float*)w;  w += 2048;
  float*    bnshift = (float*)w;  w += 2048;
  float*    b1f  = (float*)w;     w += 2048;
  float*    colsum = (float*)w;   w += (size_t)BB*KC*4;
  float*    qbuf = (float*)w;     w += (size_t)BB*KC*4;
  // optional lo planes
  ushort_t* xTl = nullptr; ushort_t* xcl = nullptr;
  size_t used = (size_t)(w - (char*)d_ws);
  if (used + big <= ws_size){ xTl = (ushort_t*)w; w += big; used += big; }
  if (used + big <= ws_size){ xcl = (ushort_t*)w; w += big; used += big; }
  int hasxTl = xTl != nullptr, hasxcl = xcl != nullptr;
  // rec outputs reuse buffers dead by then: xch (after last mgemm), xTh (after last logits)
  ushort_t* recTh = xch;
  ushort_t* recTl = xTh;

  k_transpose<<<dim3(NN/64, CC/64, BB), 256, 0, stream>>>(x, xTh, xTl, hasxTl,
      xch, xcl, hasxcl);
  k_prep<<<dim3((BB*KC*CC + 255)/256), 256, 0, stream>>>(gamma, beta, mean, var, b1,
      W1, W2, mu, bnscale, bnshift, b1f, W1h, W1l, W1Th, W1Tl, W2h, W2l, mTh, mTl);
  k_q<<<dim3(BB), 256, 0, stream>>>(b1f, mTh, mTl, qbuf, colsum);  // q iter-0; zero colsum
  for (int it = 0; it < 3; ++it){
    k_wm2<<<dim3(CC/64, BB*KC/64), 256, 0, stream>>>(W1Th, W1Tl, mTh, mTl, PTh, PTl);
    k_logits<<<dim3(NN/128, BB), 256, 0, stream>>>(xTh, xTl, hasxTl, PTh, PTl, qbuf,
        zh, zl, (it == 2) ? 1 : 0, zTh, zTl, colsum);
    k_mgemm<<<dim3(CC/128, 8, BB), 256, 0, stream>>>(xch, xcl, hasxcl, zTh, zTl, y_part);
    k_ymerge<<<dim3(KC, BB), 256, 0, stream>>>(y_part, colsum, yh, yl);
    k_wm3<<<dim3(CC/64, BB*KC/64), 256, 0, stream>>>(W1h, W1l, yh, yl, m_pre);
    k_l2q<<<dim3(KC, BB), 256, 0, stream>>>(m_pre, colsum, b1f, mch, mcl, mTh, mTl, qbuf);
  }
  k_rec<<<dim3(NN/128, CC/128, BB), 256, 0, stream>>>(zh, zl, mch, mcl, recTh, recTl);
  k_conv2<<<dim3(NN/128, CC/128, BB), 256, 0, stream>>>(W2h, W2l, recTh, recTl,
      bnscale, bnshift, out);
}